// Round 1
// baseline (1444.659 us; speedup 1.0000x reference)
//
#include <hip/hip_runtime.h>

// ---------------------------------------------------------------------------
// GIN forward: 2 GIN layers (sum aggregation + MLP + fused eval-BN) + mean
// readout + 2-layer readout MLP.
// d_out layout: [out (G*64) | h (N*64)]
// d_ws: one N*64 f32 buffer (12.8 MB) for the layer-0 intermediate.
// ---------------------------------------------------------------------------

// buf[i] = (1+eps)*in[i]   (vectorized float4, n4 = n/4)
__global__ __launch_bounds__(256) void scale_init(float* __restrict__ out,
                                                  const float* __restrict__ in,
                                                  const float* __restrict__ eps,
                                                  int n4) {
    int i = blockIdx.x * blockDim.x + threadIdx.x;
    if (i >= n4) return;
    float s = 1.0f + eps[0];
    float4 v = reinterpret_cast<const float4*>(in)[i];
    v.x *= s; v.y *= s; v.z *= s; v.w *= s;
    reinterpret_cast<float4*>(out)[i] = v;
}

// out[dst[e]*64 + :] += in[src[e]*64 + :]  via float atomics.
// 16 threads per edge, float4 each.
__global__ __launch_bounds__(256) void edge_scatter(float* __restrict__ out,
                                                    const float* __restrict__ in,
                                                    const int* __restrict__ src,
                                                    const int* __restrict__ dst,
                                                    int E) {
    int idx = blockIdx.x * blockDim.x + threadIdx.x;
    int e = idx >> 4;
    if (e >= E) return;
    int q = idx & 15;
    int s = src[e];
    int d = dst[e];
    float4 v = *reinterpret_cast<const float4*>(in + (size_t)s * 64 + q * 4);
    float* o = out + (size_t)d * 64 + q * 4;
    atomicAdd(o + 0, v.x);
    atomicAdd(o + 1, v.y);
    atomicAdd(o + 2, v.z);
    atomicAdd(o + 3, v.w);
}

// Fused GIN MLP, in-place on io (N x 64 rows).
// TWO=true : u = relu(X@Wa+ba); u = relu(u@Wb+bb); y = relu(bn_o(bn_i(u)))
// TWO=false: u = relu(X@Wa+ba);                    y = relu(bn_o(bn_i(u)))
// Block = 256 threads handles 64 rows. 4x4 register tile per thread.
template <bool TWO>
__global__ __launch_bounds__(256) void mlp_fused(
    float* __restrict__ io, int N,
    const float* __restrict__ Wa, const float* __restrict__ ba,
    const float* __restrict__ Wb, const float* __restrict__ bb,
    const float* __restrict__ gi, const float* __restrict__ bei,
    const float* __restrict__ mi, const float* __restrict__ vi,
    const float* __restrict__ go, const float* __restrict__ beo,
    const float* __restrict__ mo, const float* __restrict__ vo) {
    constexpr int PITCH = 68;  // pad 64->68 floats to break bank collisions
    __shared__ __align__(16) float Ws1[64 * 64];
    __shared__ __align__(16) float Ws2[TWO ? 64 * 64 : 4];
    __shared__ __align__(16) float Xs[64 * PITCH];   // transposed: Xs[k][r]
    __shared__ __align__(16) float Ys[TWO ? 64 * PITCH : 4];

    const int t = threadIdx.x;
    const int row0 = blockIdx.x * 64;

    // ---- stage weights (row-major [k][c]) ----
#pragma unroll
    for (int j = 0; j < 4; ++j) {
        int f4 = t + 256 * j;
        reinterpret_cast<float4*>(Ws1)[f4] = reinterpret_cast<const float4*>(Wa)[f4];
        if (TWO)
            reinterpret_cast<float4*>(Ws2)[f4] = reinterpret_cast<const float4*>(Wb)[f4];
    }
    // ---- stage X transposed: Xs[k][r] = io[row0+r][k] ----
    {
        int rs = t >> 2;        // 0..63 row within tile
        int kq = t & 3;         // float4 lane group
        int grow = row0 + rs;
#pragma unroll
        for (int j = 0; j < 4; ++j) {
            int cf4 = kq + 4 * j;  // float4 index within the 64-float row
            float4 v;
            if (grow < N)
                v = *reinterpret_cast<const float4*>(io + (size_t)grow * 64 + cf4 * 4);
            else
                v = make_float4(0.f, 0.f, 0.f, 0.f);
            int kb = cf4 * 4;
            Xs[(kb + 0) * PITCH + rs] = v.x;
            Xs[(kb + 1) * PITCH + rs] = v.y;
            Xs[(kb + 2) * PITCH + rs] = v.z;
            Xs[(kb + 3) * PITCH + rs] = v.w;
        }
    }
    __syncthreads();

    const int tr = t >> 4;  // 0..15 -> rows 4*tr..4*tr+3
    const int tc = t & 15;  // 0..15 -> cols 4*tc..4*tc+3

    float acc[4][4];
#pragma unroll
    for (int i = 0; i < 4; ++i)
#pragma unroll
        for (int j = 0; j < 4; ++j) acc[i][j] = 0.f;

#pragma unroll 4
    for (int k = 0; k < 64; ++k) {
        float4 a = *reinterpret_cast<const float4*>(&Xs[k * PITCH + 4 * tr]);
        float4 b = *reinterpret_cast<const float4*>(&Ws1[k * 64 + 4 * tc]);
        float av[4] = {a.x, a.y, a.z, a.w};
        float bv[4] = {b.x, b.y, b.z, b.w};
#pragma unroll
        for (int i = 0; i < 4; ++i)
#pragma unroll
            for (int j = 0; j < 4; ++j) acc[i][j] = fmaf(av[i], bv[j], acc[i][j]);
    }

    float u[4][4];
#pragma unroll
    for (int i = 0; i < 4; ++i)
#pragma unroll
        for (int j = 0; j < 4; ++j)
            u[i][j] = fmaxf(acc[i][j] + ba[4 * tc + j], 0.f);

    if (TWO) {
        // write Ys transposed: Ys[c][r] = u[r][c]
#pragma unroll
        for (int j = 0; j < 4; ++j) {
            float4 w = make_float4(u[0][j], u[1][j], u[2][j], u[3][j]);
            *reinterpret_cast<float4*>(&Ys[(4 * tc + j) * PITCH + 4 * tr]) = w;
        }
        __syncthreads();
#pragma unroll
        for (int i = 0; i < 4; ++i)
#pragma unroll
            for (int j = 0; j < 4; ++j) acc[i][j] = 0.f;
#pragma unroll 4
        for (int k = 0; k < 64; ++k) {
            float4 a = *reinterpret_cast<const float4*>(&Ys[k * PITCH + 4 * tr]);
            float4 b = *reinterpret_cast<const float4*>(&Ws2[k * 64 + 4 * tc]);
            float av[4] = {a.x, a.y, a.z, a.w};
            float bv[4] = {b.x, b.y, b.z, b.w};
#pragma unroll
            for (int i = 0; i < 4; ++i)
#pragma unroll
                for (int j = 0; j < 4; ++j) acc[i][j] = fmaf(av[i], bv[j], acc[i][j]);
        }
#pragma unroll
        for (int i = 0; i < 4; ++i)
#pragma unroll
            for (int j = 0; j < 4; ++j)
                u[i][j] = fmaxf(acc[i][j] + bb[4 * tc + j], 0.f);
    }

    // ---- fused double-BN affine + relu + store ----
    float sc[4], sh[4];
#pragma unroll
    for (int j = 0; j < 4; ++j) {
        int c = 4 * tc + j;
        float si = gi[c] * rsqrtf(vi[c] + 1e-5f);
        float ti = bei[c] - mi[c] * si;
        float so = go[c] * rsqrtf(vo[c] + 1e-5f);
        float to = beo[c] - mo[c] * so;
        sc[j] = si * so;
        sh[j] = ti * so + to;
    }
#pragma unroll
    for (int i = 0; i < 4; ++i) {
        int grow = row0 + 4 * tr + i;
        if (grow >= N) continue;
        float4 w;
        w.x = fmaxf(u[i][0] * sc[0] + sh[0], 0.f);
        w.y = fmaxf(u[i][1] * sc[1] + sh[1], 0.f);
        w.z = fmaxf(u[i][2] * sc[2] + sh[2], 0.f);
        w.w = fmaxf(u[i][3] * sc[3] + sh[3], 0.f);
        *reinterpret_cast<float4*>(io + (size_t)grow * 64 + 4 * tc) = w;
    }
}

__device__ __forceinline__ int lbound(const int* __restrict__ a, int n, int v) {
    int lo = 0, hi = n;
    while (lo < hi) {
        int mid = (lo + hi) >> 1;
        if (a[mid] < v) lo = mid + 1;
        else hi = mid;
    }
    return lo;
}

// One block (64 threads) per graph: segmented mean over sorted graph_ids,
// then out = relu(hg@Wr1+br1)@Wr2+br2.
__global__ __launch_bounds__(64) void readout(
    const float* __restrict__ H, const int* __restrict__ gid, int N,
    const float* __restrict__ Wr1, const float* __restrict__ br1,
    const float* __restrict__ Wr2, const float* __restrict__ br2,
    float* __restrict__ out) {
    __shared__ __align__(16) float W1s[64 * 64];
    __shared__ __align__(16) float W2s[64 * 64];
    __shared__ float hg[64];
    __shared__ float t1[64];

    const int g = blockIdx.x;
    const int c = threadIdx.x;

    for (int j = 0; j < 64; ++j) {
        W1s[j * 64 + c] = Wr1[j * 64 + c];
        W2s[j * 64 + c] = Wr2[j * 64 + c];
    }

    int lo = lbound(gid, N, g);
    int hi = lbound(gid, N, g + 1);
    float acc = 0.f;
    for (int r = lo; r < hi; ++r) acc += H[(size_t)r * 64 + c];
    float cnt = fmaxf((float)(hi - lo), 1.0f);
    hg[c] = acc / cnt;
    __syncthreads();

    float a1 = br1[c];
    for (int k = 0; k < 64; ++k) a1 = fmaf(hg[k], W1s[k * 64 + c], a1);
    t1[c] = fmaxf(a1, 0.f);
    __syncthreads();

    float a2 = br2[c];
    for (int k = 0; k < 64; ++k) a2 = fmaf(t1[k], W2s[k * 64 + c], a2);
    out[(size_t)g * 64 + c] = a2;
}

extern "C" void kernel_launch(void* const* d_in, const int* in_sizes, int n_in,
                              void* d_out, int out_size, void* d_ws, size_t ws_size,
                              hipStream_t stream) {
    const float* x    = (const float*)d_in[0];
    const int*   src  = (const int*)d_in[1];
    const int*   dst  = (const int*)d_in[2];
    const int*   gid  = (const int*)d_in[3];
    const float* eps0 = (const float*)d_in[4];
    const float* W0a  = (const float*)d_in[5];
    const float* bb0a = (const float*)d_in[6];
    const float* W0b  = (const float*)d_in[7];
    const float* bb0b = (const float*)d_in[8];
    const float* g0i  = (const float*)d_in[9];
    const float* be0i = (const float*)d_in[10];
    const float* m0i  = (const float*)d_in[11];
    const float* v0i  = (const float*)d_in[12];
    const float* g0   = (const float*)d_in[13];
    const float* be0  = (const float*)d_in[14];
    const float* m0   = (const float*)d_in[15];
    const float* v0   = (const float*)d_in[16];
    const float* eps1 = (const float*)d_in[17];
    const float* W1a  = (const float*)d_in[18];
    const float* bb1a = (const float*)d_in[19];
    const float* g1i  = (const float*)d_in[20];
    const float* be1i = (const float*)d_in[21];
    const float* m1i  = (const float*)d_in[22];
    const float* v1i  = (const float*)d_in[23];
    const float* g1   = (const float*)d_in[24];
    const float* be1  = (const float*)d_in[25];
    const float* m1   = (const float*)d_in[26];
    const float* v1   = (const float*)d_in[27];
    const float* Wr1  = (const float*)d_in[28];
    const float* br1  = (const float*)d_in[29];
    const float* Wr2  = (const float*)d_in[30];
    const float* br2  = (const float*)d_in[31];

    const int N = in_sizes[0] / 64;       // 50000
    const int E = in_sizes[1];            // 800000
    const int G = out_size / 64 - N;      // 500

    float* A   = (float*)d_ws;            // N*64 layer-0 buffer
    float* OUT = (float*)d_out;           // G*64
    float* H   = OUT + (size_t)G * 64;    // N*64 (second output: h)

    const int n4 = N * 16;                // N*64/4 float4 elements

    // ---- GIN layer 0 ----
    scale_init<<<(n4 + 255) / 256, 256, 0, stream>>>(A, x, eps0, n4);
    edge_scatter<<<(E * 16 + 255) / 256, 256, 0, stream>>>(A, x, src, dst, E);
    mlp_fused<true><<<(N + 63) / 64, 256, 0, stream>>>(
        A, N, W0a, bb0a, W0b, bb0b, g0i, be0i, m0i, v0i, g0, be0, m0, v0);

    // ---- GIN layer 1 (z and h live in d_out's h-region) ----
    scale_init<<<(n4 + 255) / 256, 256, 0, stream>>>(H, A, eps1, n4);
    edge_scatter<<<(E * 16 + 255) / 256, 256, 0, stream>>>(H, A, src, dst, E);
    mlp_fused<false><<<(N + 63) / 64, 256, 0, stream>>>(
        H, N, W1a, bb1a, nullptr, nullptr, g1i, be1i, m1i, v1i, g1, be1, m1, v1);

    // ---- readout ----
    readout<<<G, 64, 0, stream>>>(H, gid, N, Wr1, br1, Wr2, br2, OUT);
}

// Round 2
// 313.227 us; speedup vs baseline: 4.6122x; 4.6122x over previous
//
#include <hip/hip_runtime.h>

// ---------------------------------------------------------------------------
// GIN forward via on-device CSR build + gather aggregation (no float atomics).
// d_out layout: [out (G*64) | h (N*64)]
// d_ws layout:  [A (N*64 f32) | row_ptr (N+1 i32) | deg (N i32) | col (E i32)]
// ---------------------------------------------------------------------------

// ---- CSR build ------------------------------------------------------------

__global__ __launch_bounds__(256) void deg_count(int* __restrict__ deg,
                                                 const int* __restrict__ dst,
                                                 int E) {
    int e = blockIdx.x * blockDim.x + threadIdx.x;
    if (e < E) atomicAdd(&deg[dst[e]], 1);
}

// Single-block exclusive scan of deg[0..N) -> row_ptr[0..N]; row_ptr[N]=E.
__global__ __launch_bounds__(1024) void scan_deg(const int* __restrict__ deg,
                                                 int* __restrict__ row_ptr,
                                                 int N, int E) {
    __shared__ int part[1024];
    const int t = threadIdx.x;
    const int CH = (N + 1023) / 1024;
    const int lo = t * CH;
    const int hi = min(N, lo + CH);
    int s = 0;
    for (int i = lo; i < hi; ++i) s += deg[i];
    part[t] = s;
    __syncthreads();
    // Hillis-Steele inclusive scan over 1024 partials
    for (int off = 1; off < 1024; off <<= 1) {
        int v = (t >= off) ? part[t - off] : 0;
        __syncthreads();
        part[t] += v;
        __syncthreads();
    }
    int base = (t > 0) ? part[t - 1] : 0;  // exclusive prefix of this chunk
    for (int i = lo; i < hi; ++i) {
        row_ptr[i] = base;
        base += deg[i];
    }
    if (t == 0) row_ptr[N] = E;
}

__global__ __launch_bounds__(256) void csr_fill(int* __restrict__ col,
                                                int* __restrict__ cnt,
                                                const int* __restrict__ row_ptr,
                                                const int* __restrict__ src,
                                                const int* __restrict__ dst,
                                                int E) {
    int e = blockIdx.x * blockDim.x + threadIdx.x;
    if (e >= E) return;
    int d = dst[e];
    int pos = row_ptr[d] + atomicAdd(&cnt[d], 1);
    col[pos] = src[e];
}

// ---- gather aggregation: out[n] = (1+eps)*in[n] + sum_{nbr} in[nbr] -------
// One 64-lane wave per node, lane = feature column.
__global__ __launch_bounds__(256) void aggregate(float* __restrict__ out,
                                                 const float* __restrict__ in,
                                                 const int* __restrict__ row_ptr,
                                                 const int* __restrict__ col,
                                                 const float* __restrict__ eps,
                                                 int N) {
    const int n = blockIdx.x * 4 + (threadIdx.x >> 6);
    const int lane = threadIdx.x & 63;
    if (n >= N) return;
    const int lo = row_ptr[n];
    const int hi = row_ptr[n + 1];
    float acc = (1.0f + eps[0]) * in[(size_t)n * 64 + lane];
    int j = lo;
    for (; j + 4 <= hi; j += 4) {
        int c0 = col[j], c1 = col[j + 1], c2 = col[j + 2], c3 = col[j + 3];
        float a0 = in[(size_t)c0 * 64 + lane];
        float a1 = in[(size_t)c1 * 64 + lane];
        float a2 = in[(size_t)c2 * 64 + lane];
        float a3 = in[(size_t)c3 * 64 + lane];
        acc += (a0 + a1) + (a2 + a3);
    }
    for (; j < hi; ++j) acc += in[(size_t)col[j] * 64 + lane];
    out[(size_t)n * 64 + lane] = acc;
}

// ---- fused GIN MLP (unchanged from R1) ------------------------------------
template <bool TWO>
__global__ __launch_bounds__(256) void mlp_fused(
    float* __restrict__ io, int N,
    const float* __restrict__ Wa, const float* __restrict__ ba,
    const float* __restrict__ Wb, const float* __restrict__ bb,
    const float* __restrict__ gi, const float* __restrict__ bei,
    const float* __restrict__ mi, const float* __restrict__ vi,
    const float* __restrict__ go, const float* __restrict__ beo,
    const float* __restrict__ mo, const float* __restrict__ vo) {
    constexpr int PITCH = 68;
    __shared__ __align__(16) float Ws1[64 * 64];
    __shared__ __align__(16) float Ws2[TWO ? 64 * 64 : 4];
    __shared__ __align__(16) float Xs[64 * PITCH];
    __shared__ __align__(16) float Ys[TWO ? 64 * PITCH : 4];

    const int t = threadIdx.x;
    const int row0 = blockIdx.x * 64;

#pragma unroll
    for (int j = 0; j < 4; ++j) {
        int f4 = t + 256 * j;
        reinterpret_cast<float4*>(Ws1)[f4] = reinterpret_cast<const float4*>(Wa)[f4];
        if (TWO)
            reinterpret_cast<float4*>(Ws2)[f4] = reinterpret_cast<const float4*>(Wb)[f4];
    }
    {
        int rs = t >> 2;
        int kq = t & 3;
        int grow = row0 + rs;
#pragma unroll
        for (int j = 0; j < 4; ++j) {
            int cf4 = kq + 4 * j;
            float4 v;
            if (grow < N)
                v = *reinterpret_cast<const float4*>(io + (size_t)grow * 64 + cf4 * 4);
            else
                v = make_float4(0.f, 0.f, 0.f, 0.f);
            int kb = cf4 * 4;
            Xs[(kb + 0) * PITCH + rs] = v.x;
            Xs[(kb + 1) * PITCH + rs] = v.y;
            Xs[(kb + 2) * PITCH + rs] = v.z;
            Xs[(kb + 3) * PITCH + rs] = v.w;
        }
    }
    __syncthreads();

    const int tr = t >> 4;
    const int tc = t & 15;

    float acc[4][4];
#pragma unroll
    for (int i = 0; i < 4; ++i)
#pragma unroll
        for (int j = 0; j < 4; ++j) acc[i][j] = 0.f;

#pragma unroll 4
    for (int k = 0; k < 64; ++k) {
        float4 a = *reinterpret_cast<const float4*>(&Xs[k * PITCH + 4 * tr]);
        float4 b = *reinterpret_cast<const float4*>(&Ws1[k * 64 + 4 * tc]);
        float av[4] = {a.x, a.y, a.z, a.w};
        float bv[4] = {b.x, b.y, b.z, b.w};
#pragma unroll
        for (int i = 0; i < 4; ++i)
#pragma unroll
            for (int j = 0; j < 4; ++j) acc[i][j] = fmaf(av[i], bv[j], acc[i][j]);
    }

    float u[4][4];
#pragma unroll
    for (int i = 0; i < 4; ++i)
#pragma unroll
        for (int j = 0; j < 4; ++j)
            u[i][j] = fmaxf(acc[i][j] + ba[4 * tc + j], 0.f);

    if (TWO) {
#pragma unroll
        for (int j = 0; j < 4; ++j) {
            float4 w = make_float4(u[0][j], u[1][j], u[2][j], u[3][j]);
            *reinterpret_cast<float4*>(&Ys[(4 * tc + j) * PITCH + 4 * tr]) = w;
        }
        __syncthreads();
#pragma unroll
        for (int i = 0; i < 4; ++i)
#pragma unroll
            for (int j = 0; j < 4; ++j) acc[i][j] = 0.f;
#pragma unroll 4
        for (int k = 0; k < 64; ++k) {
            float4 a = *reinterpret_cast<const float4*>(&Ys[k * PITCH + 4 * tr]);
            float4 b = *reinterpret_cast<const float4*>(&Ws2[k * 64 + 4 * tc]);
            float av[4] = {a.x, a.y, a.z, a.w};
            float bv[4] = {b.x, b.y, b.z, b.w};
#pragma unroll
            for (int i = 0; i < 4; ++i)
#pragma unroll
                for (int j = 0; j < 4; ++j) acc[i][j] = fmaf(av[i], bv[j], acc[i][j]);
        }
#pragma unroll
        for (int i = 0; i < 4; ++i)
#pragma unroll
            for (int j = 0; j < 4; ++j)
                u[i][j] = fmaxf(acc[i][j] + bb[4 * tc + j], 0.f);
    }

    float sc[4], sh[4];
#pragma unroll
    for (int j = 0; j < 4; ++j) {
        int c = 4 * tc + j;
        float si = gi[c] * rsqrtf(vi[c] + 1e-5f);
        float ti = bei[c] - mi[c] * si;
        float so = go[c] * rsqrtf(vo[c] + 1e-5f);
        float to = beo[c] - mo[c] * so;
        sc[j] = si * so;
        sh[j] = ti * so + to;
    }
#pragma unroll
    for (int i = 0; i < 4; ++i) {
        int grow = row0 + 4 * tr + i;
        if (grow >= N) continue;
        float4 w;
        w.x = fmaxf(u[i][0] * sc[0] + sh[0], 0.f);
        w.y = fmaxf(u[i][1] * sc[1] + sh[1], 0.f);
        w.z = fmaxf(u[i][2] * sc[2] + sh[2], 0.f);
        w.w = fmaxf(u[i][3] * sc[3] + sh[3], 0.f);
        *reinterpret_cast<float4*>(io + (size_t)grow * 64 + 4 * tc) = w;
    }
}

__device__ __forceinline__ int lbound(const int* __restrict__ a, int n, int v) {
    int lo = 0, hi = n;
    while (lo < hi) {
        int mid = (lo + hi) >> 1;
        if (a[mid] < v) lo = mid + 1;
        else hi = mid;
    }
    return lo;
}

__global__ __launch_bounds__(64) void readout(
    const float* __restrict__ H, const int* __restrict__ gid, int N,
    const float* __restrict__ Wr1, const float* __restrict__ br1,
    const float* __restrict__ Wr2, const float* __restrict__ br2,
    float* __restrict__ out) {
    __shared__ __align__(16) float W1s[64 * 64];
    __shared__ __align__(16) float W2s[64 * 64];
    __shared__ float hg[64];
    __shared__ float t1[64];

    const int g = blockIdx.x;
    const int c = threadIdx.x;

    for (int j = 0; j < 64; ++j) {
        W1s[j * 64 + c] = Wr1[j * 64 + c];
        W2s[j * 64 + c] = Wr2[j * 64 + c];
    }

    int lo = lbound(gid, N, g);
    int hi = lbound(gid, N, g + 1);
    float acc = 0.f;
    for (int r = lo; r < hi; ++r) acc += H[(size_t)r * 64 + c];
    float cnt = fmaxf((float)(hi - lo), 1.0f);
    hg[c] = acc / cnt;
    __syncthreads();

    float a1 = br1[c];
    for (int k = 0; k < 64; ++k) a1 = fmaf(hg[k], W1s[k * 64 + c], a1);
    t1[c] = fmaxf(a1, 0.f);
    __syncthreads();

    float a2 = br2[c];
    for (int k = 0; k < 64; ++k) a2 = fmaf(t1[k], W2s[k * 64 + c], a2);
    out[(size_t)g * 64 + c] = a2;
}

extern "C" void kernel_launch(void* const* d_in, const int* in_sizes, int n_in,
                              void* d_out, int out_size, void* d_ws, size_t ws_size,
                              hipStream_t stream) {
    const float* x    = (const float*)d_in[0];
    const int*   src  = (const int*)d_in[1];
    const int*   dst  = (const int*)d_in[2];
    const int*   gid  = (const int*)d_in[3];
    const float* eps0 = (const float*)d_in[4];
    const float* W0a  = (const float*)d_in[5];
    const float* bb0a = (const float*)d_in[6];
    const float* W0b  = (const float*)d_in[7];
    const float* bb0b = (const float*)d_in[8];
    const float* g0i  = (const float*)d_in[9];
    const float* be0i = (const float*)d_in[10];
    const float* m0i  = (const float*)d_in[11];
    const float* v0i  = (const float*)d_in[12];
    const float* g0   = (const float*)d_in[13];
    const float* be0  = (const float*)d_in[14];
    const float* m0   = (const float*)d_in[15];
    const float* v0   = (const float*)d_in[16];
    const float* eps1 = (const float*)d_in[17];
    const float* W1a  = (const float*)d_in[18];
    const float* bb1a = (const float*)d_in[19];
    const float* g1i  = (const float*)d_in[20];
    const float* be1i = (const float*)d_in[21];
    const float* m1i  = (const float*)d_in[22];
    const float* v1i  = (const float*)d_in[23];
    const float* g1   = (const float*)d_in[24];
    const float* be1  = (const float*)d_in[25];
    const float* m1   = (const float*)d_in[26];
    const float* v1   = (const float*)d_in[27];
    const float* Wr1  = (const float*)d_in[28];
    const float* br1  = (const float*)d_in[29];
    const float* Wr2  = (const float*)d_in[30];
    const float* br2  = (const float*)d_in[31];

    const int N = in_sizes[0] / 64;       // 50000
    const int E = in_sizes[1];            // 800000
    const int G = out_size / 64 - N;      // 500

    // ws layout (16-byte aligned chunks)
    char* ws = (char*)d_ws;
    float* A       = (float*)ws;                       ws += (size_t)N * 64 * 4;
    int*   row_ptr = (int*)ws;                         ws += ((size_t)N + 4) * 4;
    int*   deg     = (int*)ws;                         ws += ((size_t)N + 4) * 4;
    int*   col     = (int*)ws;

    float* OUT = (float*)d_out;
    float* H   = OUT + (size_t)G * 64;

    // ---- build CSR (once; shared by both layers) ----
    hipMemsetAsync(deg, 0, (size_t)N * 4, stream);
    deg_count<<<(E + 255) / 256, 256, 0, stream>>>(deg, dst, E);
    scan_deg<<<1, 1024, 0, stream>>>(deg, row_ptr, N, E);
    hipMemsetAsync(deg, 0, (size_t)N * 4, stream);
    csr_fill<<<(E + 255) / 256, 256, 0, stream>>>(col, deg, row_ptr, src, dst, E);

    // ---- GIN layer 0 ----
    aggregate<<<(N + 3) / 4, 256, 0, stream>>>(A, x, row_ptr, col, eps0, N);
    mlp_fused<true><<<(N + 63) / 64, 256, 0, stream>>>(
        A, N, W0a, bb0a, W0b, bb0b, g0i, be0i, m0i, v0i, g0, be0, m0, v0);

    // ---- GIN layer 1 ----
    aggregate<<<(N + 3) / 4, 256, 0, stream>>>(H, A, row_ptr, col, eps1, N);
    mlp_fused<false><<<(N + 63) / 64, 256, 0, stream>>>(
        H, N, W1a, bb1a, nullptr, nullptr, g1i, be1i, m1i, v1i, g1, be1, m1, v1);

    // ---- readout ----
    readout<<<G, 64, 0, stream>>>(H, gid, N, Wr1, br1, Wr2, br2, OUT);
}

// Round 3
// 253.742 us; speedup vs baseline: 5.6934x; 1.2344x over previous
//
#include <hip/hip_runtime.h>

// ---------------------------------------------------------------------------
// GIN forward via on-device CSR build + gather aggregation (no float atomics).
// d_out layout: [out (G*64) | h (N*64)]
// d_ws layout:  [A (N*64 f32) | row_ptr (N+1 i32) | deg (N i32) | col (E i32)]
// ---------------------------------------------------------------------------

// ---- CSR build ------------------------------------------------------------

__global__ __launch_bounds__(256) void deg_count(int* __restrict__ deg,
                                                 const int* __restrict__ dst,
                                                 int E) {
    int e = blockIdx.x * blockDim.x + threadIdx.x;
    if (e < E) atomicAdd(&deg[dst[e]], 1);
}

// Single-block exclusive scan of deg[0..N) -> row_ptr[0..N]; row_ptr[N]=E.
// Coalesced: tiles of 4096 (1024 threads x int4), wave-scan + LDS warp scan.
__global__ __launch_bounds__(1024) void scan_deg(const int* __restrict__ deg,
                                                 int* __restrict__ row_ptr,
                                                 int N, int E) {
    __shared__ int warp_sums[16];
    const int t = threadIdx.x;
    const int lane = t & 63;
    const int wid = t >> 6;

    int base = 0;
    const int ntiles = (N + 4095) / 4096;
    for (int tile = 0; tile < ntiles; ++tile) {
        const int i0 = tile * 4096 + t * 4;
        int4 v = make_int4(0, 0, 0, 0);
        if (i0 + 3 < N) {
            v = *reinterpret_cast<const int4*>(deg + i0);
        } else if (i0 < N) {
            v.x = deg[i0];
            if (i0 + 1 < N) v.y = deg[i0 + 1];
            if (i0 + 2 < N) v.z = deg[i0 + 2];
        }
        const int s = v.x + v.y + v.z + v.w;

        // inclusive 64-lane wave scan of s
        int sc = s;
#pragma unroll
        for (int off = 1; off < 64; off <<= 1) {
            int u = __shfl_up(sc, off);
            if (lane >= off) sc += u;
        }
        if (lane == 63) warp_sums[wid] = sc;
        __syncthreads();
        if (wid == 0) {
            int ws = (lane < 16) ? warp_sums[lane] : 0;
#pragma unroll
            for (int off = 1; off < 16; off <<= 1) {
                int u = __shfl_up(ws, off);
                if (lane >= off) ws += u;
            }
            if (lane < 16) warp_sums[lane] = ws;
        }
        __syncthreads();

        const int excl = base + (sc - s) + (wid > 0 ? warp_sums[wid - 1] : 0);
        int4 o;
        o.x = excl;
        o.y = excl + v.x;
        o.z = excl + v.x + v.y;
        o.w = excl + v.x + v.y + v.z;
        if (i0 + 3 < N) {
            *reinterpret_cast<int4*>(row_ptr + i0) = o;
        } else if (i0 < N) {
            row_ptr[i0] = o.x;
            if (i0 + 1 < N) row_ptr[i0 + 1] = o.y;
            if (i0 + 2 < N) row_ptr[i0 + 2] = o.z;
        }
        base += warp_sums[15];
        __syncthreads();  // protect warp_sums before next tile overwrites
    }
    if (t == 0) row_ptr[N] = E;
}

__global__ __launch_bounds__(256) void csr_fill(int* __restrict__ col,
                                                int* __restrict__ cnt,
                                                const int* __restrict__ row_ptr,
                                                const int* __restrict__ src,
                                                const int* __restrict__ dst,
                                                int E) {
    int e = blockIdx.x * blockDim.x + threadIdx.x;
    if (e >= E) return;
    int d = dst[e];
    int pos = row_ptr[d] + atomicAdd(&cnt[d], 1);
    col[pos] = src[e];
}

// ---- gather aggregation: out[n] = (1+eps)*in[n] + sum_{nbr} in[nbr] -------
// One 64-lane wave per node, lane = feature column.
__global__ __launch_bounds__(256) void aggregate(float* __restrict__ out,
                                                 const float* __restrict__ in,
                                                 const int* __restrict__ row_ptr,
                                                 const int* __restrict__ col,
                                                 const float* __restrict__ eps,
                                                 int N) {
    const int n = blockIdx.x * 4 + (threadIdx.x >> 6);
    const int lane = threadIdx.x & 63;
    if (n >= N) return;
    const int lo = row_ptr[n];
    const int hi = row_ptr[n + 1];
    float acc = (1.0f + eps[0]) * in[(size_t)n * 64 + lane];
    int j = lo;
    for (; j + 4 <= hi; j += 4) {
        int c0 = col[j], c1 = col[j + 1], c2 = col[j + 2], c3 = col[j + 3];
        float a0 = in[(size_t)c0 * 64 + lane];
        float a1 = in[(size_t)c1 * 64 + lane];
        float a2 = in[(size_t)c2 * 64 + lane];
        float a3 = in[(size_t)c3 * 64 + lane];
        acc += (a0 + a1) + (a2 + a3);
    }
    for (; j < hi; ++j) acc += in[(size_t)col[j] * 64 + lane];
    out[(size_t)n * 64 + lane] = acc;
}

// ---- fused GIN MLP --------------------------------------------------------
template <bool TWO>
__global__ __launch_bounds__(256) void mlp_fused(
    float* __restrict__ io, int N,
    const float* __restrict__ Wa, const float* __restrict__ ba,
    const float* __restrict__ Wb, const float* __restrict__ bb,
    const float* __restrict__ gi, const float* __restrict__ bei,
    const float* __restrict__ mi, const float* __restrict__ vi,
    const float* __restrict__ go, const float* __restrict__ beo,
    const float* __restrict__ mo, const float* __restrict__ vo) {
    constexpr int PITCH = 68;
    __shared__ __align__(16) float Ws1[64 * 64];
    __shared__ __align__(16) float Ws2[TWO ? 64 * 64 : 4];
    __shared__ __align__(16) float Xs[64 * PITCH];
    __shared__ __align__(16) float Ys[TWO ? 64 * PITCH : 4];

    const int t = threadIdx.x;
    const int row0 = blockIdx.x * 64;

#pragma unroll
    for (int j = 0; j < 4; ++j) {
        int f4 = t + 256 * j;
        reinterpret_cast<float4*>(Ws1)[f4] = reinterpret_cast<const float4*>(Wa)[f4];
        if (TWO)
            reinterpret_cast<float4*>(Ws2)[f4] = reinterpret_cast<const float4*>(Wb)[f4];
    }
    {
        int rs = t >> 2;
        int kq = t & 3;
        int grow = row0 + rs;
#pragma unroll
        for (int j = 0; j < 4; ++j) {
            int cf4 = kq + 4 * j;
            float4 v;
            if (grow < N)
                v = *reinterpret_cast<const float4*>(io + (size_t)grow * 64 + cf4 * 4);
            else
                v = make_float4(0.f, 0.f, 0.f, 0.f);
            int kb = cf4 * 4;
            Xs[(kb + 0) * PITCH + rs] = v.x;
            Xs[(kb + 1) * PITCH + rs] = v.y;
            Xs[(kb + 2) * PITCH + rs] = v.z;
            Xs[(kb + 3) * PITCH + rs] = v.w;
        }
    }
    __syncthreads();

    const int tr = t >> 4;
    const int tc = t & 15;

    float acc[4][4];
#pragma unroll
    for (int i = 0; i < 4; ++i)
#pragma unroll
        for (int j = 0; j < 4; ++j) acc[i][j] = 0.f;

#pragma unroll 4
    for (int k = 0; k < 64; ++k) {
        float4 a = *reinterpret_cast<const float4*>(&Xs[k * PITCH + 4 * tr]);
        float4 b = *reinterpret_cast<const float4*>(&Ws1[k * 64 + 4 * tc]);
        float av[4] = {a.x, a.y, a.z, a.w};
        float bv[4] = {b.x, b.y, b.z, b.w};
#pragma unroll
        for (int i = 0; i < 4; ++i)
#pragma unroll
            for (int j = 0; j < 4; ++j) acc[i][j] = fmaf(av[i], bv[j], acc[i][j]);
    }

    float u[4][4];
#pragma unroll
    for (int i = 0; i < 4; ++i)
#pragma unroll
        for (int j = 0; j < 4; ++j)
            u[i][j] = fmaxf(acc[i][j] + ba[4 * tc + j], 0.f);

    if (TWO) {
#pragma unroll
        for (int j = 0; j < 4; ++j) {
            float4 w = make_float4(u[0][j], u[1][j], u[2][j], u[3][j]);
            *reinterpret_cast<float4*>(&Ys[(4 * tc + j) * PITCH + 4 * tr]) = w;
        }
        __syncthreads();
#pragma unroll
        for (int i = 0; i < 4; ++i)
#pragma unroll
            for (int j = 0; j < 4; ++j) acc[i][j] = 0.f;
#pragma unroll 4
        for (int k = 0; k < 64; ++k) {
            float4 a = *reinterpret_cast<const float4*>(&Ys[k * PITCH + 4 * tr]);
            float4 b = *reinterpret_cast<const float4*>(&Ws2[k * 64 + 4 * tc]);
            float av[4] = {a.x, a.y, a.z, a.w};
            float bv[4] = {b.x, b.y, b.z, b.w};
#pragma unroll
            for (int i = 0; i < 4; ++i)
#pragma unroll
                for (int j = 0; j < 4; ++j) acc[i][j] = fmaf(av[i], bv[j], acc[i][j]);
        }
#pragma unroll
        for (int i = 0; i < 4; ++i)
#pragma unroll
            for (int j = 0; j < 4; ++j)
                u[i][j] = fmaxf(acc[i][j] + bb[4 * tc + j], 0.f);
    }

    float sc[4], sh[4];
#pragma unroll
    for (int j = 0; j < 4; ++j) {
        int c = 4 * tc + j;
        float si = gi[c] * rsqrtf(vi[c] + 1e-5f);
        float ti = bei[c] - mi[c] * si;
        float so = go[c] * rsqrtf(vo[c] + 1e-5f);
        float to = beo[c] - mo[c] * so;
        sc[j] = si * so;
        sh[j] = ti * so + to;
    }
#pragma unroll
    for (int i = 0; i < 4; ++i) {
        int grow = row0 + 4 * tr + i;
        if (grow >= N) continue;
        float4 w;
        w.x = fmaxf(u[i][0] * sc[0] + sh[0], 0.f);
        w.y = fmaxf(u[i][1] * sc[1] + sh[1], 0.f);
        w.z = fmaxf(u[i][2] * sc[2] + sh[2], 0.f);
        w.w = fmaxf(u[i][3] * sc[3] + sh[3], 0.f);
        *reinterpret_cast<float4*>(io + (size_t)grow * 64 + 4 * tc) = w;
    }
}

__device__ __forceinline__ int lbound(const int* __restrict__ a, int n, int v) {
    int lo = 0, hi = n;
    while (lo < hi) {
        int mid = (lo + hi) >> 1;
        if (a[mid] < v) lo = mid + 1;
        else hi = mid;
    }
    return lo;
}

__global__ __launch_bounds__(64) void readout(
    const float* __restrict__ H, const int* __restrict__ gid, int N,
    const float* __restrict__ Wr1, const float* __restrict__ br1,
    const float* __restrict__ Wr2, const float* __restrict__ br2,
    float* __restrict__ out) {
    __shared__ __align__(16) float W1s[64 * 64];
    __shared__ __align__(16) float W2s[64 * 64];
    __shared__ float hg[64];
    __shared__ float t1[64];

    const int g = blockIdx.x;
    const int c = threadIdx.x;

    for (int j = 0; j < 64; ++j) {
        W1s[j * 64 + c] = Wr1[j * 64 + c];
        W2s[j * 64 + c] = Wr2[j * 64 + c];
    }

    int lo = lbound(gid, N, g);
    int hi = lbound(gid, N, g + 1);
    float acc = 0.f;
    for (int r = lo; r < hi; ++r) acc += H[(size_t)r * 64 + c];
    float cnt = fmaxf((float)(hi - lo), 1.0f);
    hg[c] = acc / cnt;
    __syncthreads();

    float a1 = br1[c];
    for (int k = 0; k < 64; ++k) a1 = fmaf(hg[k], W1s[k * 64 + c], a1);
    t1[c] = fmaxf(a1, 0.f);
    __syncthreads();

    float a2 = br2[c];
    for (int k = 0; k < 64; ++k) a2 = fmaf(t1[k], W2s[k * 64 + c], a2);
    out[(size_t)g * 64 + c] = a2;
}

extern "C" void kernel_launch(void* const* d_in, const int* in_sizes, int n_in,
                              void* d_out, int out_size, void* d_ws, size_t ws_size,
                              hipStream_t stream) {
    const float* x    = (const float*)d_in[0];
    const int*   src  = (const int*)d_in[1];
    const int*   dst  = (const int*)d_in[2];
    const int*   gid  = (const int*)d_in[3];
    const float* eps0 = (const float*)d_in[4];
    const float* W0a  = (const float*)d_in[5];
    const float* bb0a = (const float*)d_in[6];
    const float* W0b  = (const float*)d_in[7];
    const float* bb0b = (const float*)d_in[8];
    const float* g0i  = (const float*)d_in[9];
    const float* be0i = (const float*)d_in[10];
    const float* m0i  = (const float*)d_in[11];
    const float* v0i  = (const float*)d_in[12];
    const float* g0   = (const float*)d_in[13];
    const float* be0  = (const float*)d_in[14];
    const float* m0   = (const float*)d_in[15];
    const float* v0   = (const float*)d_in[16];
    const float* eps1 = (const float*)d_in[17];
    const float* W1a  = (const float*)d_in[18];
    const float* bb1a = (const float*)d_in[19];
    const float* g1i  = (const float*)d_in[20];
    const float* be1i = (const float*)d_in[21];
    const float* m1i  = (const float*)d_in[22];
    const float* v1i  = (const float*)d_in[23];
    const float* g1   = (const float*)d_in[24];
    const float* be1  = (const float*)d_in[25];
    const float* m1   = (const float*)d_in[26];
    const float* v1   = (const float*)d_in[27];
    const float* Wr1  = (const float*)d_in[28];
    const float* br1  = (const float*)d_in[29];
    const float* Wr2  = (const float*)d_in[30];
    const float* br2  = (const float*)d_in[31];

    const int N = in_sizes[0] / 64;       // 50000
    const int E = in_sizes[1];            // 800000
    const int G = out_size / 64 - N;      // 500

    // ws layout (16-byte aligned chunks)
    char* ws = (char*)d_ws;
    float* A       = (float*)ws;                       ws += (size_t)N * 64 * 4;
    int*   row_ptr = (int*)ws;                         ws += ((size_t)N + 4) * 4;
    int*   deg     = (int*)ws;                         ws += ((size_t)N + 4) * 4;
    int*   col     = (int*)ws;

    float* OUT = (float*)d_out;
    float* H   = OUT + (size_t)G * 64;

    // ---- build CSR (once; shared by both layers) ----
    hipMemsetAsync(deg, 0, (size_t)N * 4, stream);
    deg_count<<<(E + 255) / 256, 256, 0, stream>>>(deg, dst, E);
    scan_deg<<<1, 1024, 0, stream>>>(deg, row_ptr, N, E);
    hipMemsetAsync(deg, 0, (size_t)N * 4, stream);
    csr_fill<<<(E + 255) / 256, 256, 0, stream>>>(col, deg, row_ptr, src, dst, E);

    // ---- GIN layer 0 ----
    aggregate<<<(N + 3) / 4, 256, 0, stream>>>(A, x, row_ptr, col, eps0, N);
    mlp_fused<true><<<(N + 63) / 64, 256, 0, stream>>>(
        A, N, W0a, bb0a, W0b, bb0b, g0i, be0i, m0i, v0i, g0, be0, m0, v0);

    // ---- GIN layer 1 ----
    aggregate<<<(N + 3) / 4, 256, 0, stream>>>(H, A, row_ptr, col, eps1, N);
    mlp_fused<false><<<(N + 63) / 64, 256, 0, stream>>>(
        H, N, W1a, bb1a, nullptr, nullptr, g1i, be1i, m1i, v1i, g1, be1, m1, v1);

    // ---- readout ----
    readout<<<G, 64, 0, stream>>>(H, gid, N, Wr1, br1, Wr2, br2, OUT);
}

// Round 4
// 190.307 us; speedup vs baseline: 7.5912x; 1.3333x over previous
//
#include <hip/hip_runtime.h>

// ---------------------------------------------------------------------------
// GIN forward via bucketed on-device CSR build + gather aggregation.
// d_out layout: [out (G*64) | h (N*64)]
// d_ws layout:  [A (N*64 f32) | row_ptr | ebase | cursor | ghist | ebuf(E u32)]
// Bucket = dst >> 7 (128 nodes per bucket).  Requires N < 65536 (ids pack u16).
// ---------------------------------------------------------------------------

#define EPB 2048   // edges per block in hist/scatter
#define MAXB 512   // max buckets supported (N <= 65536)

// ---- Phase A: global bucket histogram (LDS-aggregated) --------------------
__global__ __launch_bounds__(256) void bucket_hist(int* __restrict__ gh,
                                                   const int* __restrict__ dst,
                                                   int E) {
    __shared__ int h[MAXB];
    const int t = threadIdx.x;
    for (int i = t; i < MAXB; i += 256) h[i] = 0;
    __syncthreads();
    const int base = blockIdx.x * EPB;
#pragma unroll
    for (int i = 0; i < 8; ++i) {
        int e = base + i * 256 + t;
        if (e < E) atomicAdd(&h[dst[e] >> 7], 1);
    }
    __syncthreads();
    for (int i = t; i < MAXB; i += 256) {
        int v = h[i];
        if (v) atomicAdd(&gh[i], v);
    }
}

// ---- Phase B: single-block scan of bucket counts -> ebase (+cursor copy) --
__global__ __launch_bounds__(1024) void scan_small(const int* __restrict__ in,
                                                   int* __restrict__ ebase,
                                                   int* __restrict__ cursor,
                                                   int n, int total) {
    __shared__ int arr[1024];
    const int t = threadIdx.x;
    int v = (t < n) ? in[t] : 0;
    arr[t] = v;
    __syncthreads();
    for (int s = 1; s < 1024; s <<= 1) {
        int u = (t >= s) ? arr[t - s] : 0;
        __syncthreads();
        arr[t] += u;
        __syncthreads();
    }
    int excl = (t > 0) ? arr[t - 1] : 0;
    if (t < n) {
        ebase[t] = excl;
        cursor[t] = excl;
    }
    if (t == 0) ebase[n] = total;
}

// ---- Phase C: scatter packed (src<<16|dst) into bucket-grouped ebuf -------
__global__ __launch_bounds__(256) void bin_scatter(unsigned* __restrict__ ebuf,
                                                   int* __restrict__ cursor,
                                                   const int* __restrict__ src,
                                                   const int* __restrict__ dst,
                                                   int E) {
    __shared__ int h[MAXB];
    __shared__ int gb[MAXB];
    const int t = threadIdx.x;
    for (int i = t; i < MAXB; i += 256) h[i] = 0;
    __syncthreads();
    const int base = blockIdx.x * EPB;
    int sv[8], dv[8];
#pragma unroll
    for (int i = 0; i < 8; ++i) {
        int e = base + i * 256 + t;
        if (e < E) {
            sv[i] = src[e];
            dv[i] = dst[e];
            atomicAdd(&h[dv[i] >> 7], 1);
        } else {
            dv[i] = -1;
        }
    }
    __syncthreads();
    for (int i = t; i < MAXB; i += 256) {
        int v = h[i];
        gb[i] = v ? atomicAdd(&cursor[i], v) : 0;
        h[i] = 0;
    }
    __syncthreads();
#pragma unroll
    for (int i = 0; i < 8; ++i) {
        if (dv[i] >= 0) {
            int b = dv[i] >> 7;
            int p = atomicAdd(&h[b], 1);
            ebuf[gb[b] + p] = ((unsigned)sv[i] << 16) | (unsigned)dv[i];
        }
    }
}

// ---- Phase D: per-bucket row_ptr + in-place col fill (LDS-staged) ---------
__global__ __launch_bounds__(256) void bucket_fill(unsigned* __restrict__ ebuf,
                                                   const int* __restrict__ ebase,
                                                   int* __restrict__ row_ptr,
                                                   int N, int E) {
    __shared__ unsigned pairLDS[4096];
    __shared__ unsigned colLDS[4096];
    __shared__ int deg[128], off[128], cur[128];
    const int b = blockIdx.x;
    const int t = threadIdx.x;
    const int lo = ebase[b];
    const int hi = ebase[b + 1];
    const int m = hi - lo;
    const int nb0 = b << 7;

    if (t < 128) deg[t] = 0;
    __syncthreads();
    for (int k = t; k < m; k += 256) {
        unsigned v = ebuf[lo + k];
        pairLDS[k] = v;
        atomicAdd(&deg[(int)(v & 0xFFFFu) - nb0], 1);
    }
    __syncthreads();
    // inclusive scan of deg -> off
    if (t < 128) off[t] = deg[t];
    __syncthreads();
    for (int s = 1; s < 128; s <<= 1) {
        int u = 0;
        if (t < 128 && t >= s) u = off[t - s];
        __syncthreads();
        if (t < 128) off[t] += u;
        __syncthreads();
    }
    if (t < 128) {
        int excl = off[t] - deg[t];
        cur[t] = excl;
        int node = nb0 + t;
        if (node <= N) row_ptr[node] = lo + excl;
    }
    __syncthreads();
    for (int k = t; k < m; k += 256) {
        unsigned v = pairLDS[k];
        int dl = (int)(v & 0xFFFFu) - nb0;
        int p = atomicAdd(&cur[dl], 1);
        colLDS[p] = v >> 16;
    }
    __syncthreads();
    for (int k = t; k < m; k += 256) ebuf[lo + k] = colLDS[k];
    // row_ptr[N] is written by the bucket containing node N (excl==m there).
}

// ---- gather aggregation: out[n] = (1+eps)*in[n] + sum_{nbr} in[nbr] -------
__global__ __launch_bounds__(256) void aggregate(float* __restrict__ out,
                                                 const float* __restrict__ in,
                                                 const int* __restrict__ row_ptr,
                                                 const unsigned* __restrict__ col,
                                                 const float* __restrict__ eps,
                                                 int N) {
    const int n = blockIdx.x * 4 + (threadIdx.x >> 6);
    const int lane = threadIdx.x & 63;
    if (n >= N) return;
    const int lo = row_ptr[n];
    const int hi = row_ptr[n + 1];
    float acc = (1.0f + eps[0]) * in[(size_t)n * 64 + lane];
    int j = lo;
    for (; j + 4 <= hi; j += 4) {
        unsigned c0 = col[j], c1 = col[j + 1], c2 = col[j + 2], c3 = col[j + 3];
        float a0 = in[(size_t)c0 * 64 + lane];
        float a1 = in[(size_t)c1 * 64 + lane];
        float a2 = in[(size_t)c2 * 64 + lane];
        float a3 = in[(size_t)c3 * 64 + lane];
        acc += (a0 + a1) + (a2 + a3);
    }
    for (; j < hi; ++j) acc += in[(size_t)col[j] * 64 + lane];
    out[(size_t)n * 64 + lane] = acc;
}

// ---- fused GIN MLP --------------------------------------------------------
template <bool TWO>
__global__ __launch_bounds__(256) void mlp_fused(
    float* __restrict__ io, int N,
    const float* __restrict__ Wa, const float* __restrict__ ba,
    const float* __restrict__ Wb, const float* __restrict__ bb,
    const float* __restrict__ gi, const float* __restrict__ bei,
    const float* __restrict__ mi, const float* __restrict__ vi,
    const float* __restrict__ go, const float* __restrict__ beo,
    const float* __restrict__ mo, const float* __restrict__ vo) {
    constexpr int PITCH = 68;
    __shared__ __align__(16) float Ws1[64 * 64];
    __shared__ __align__(16) float Ws2[TWO ? 64 * 64 : 4];
    __shared__ __align__(16) float Xs[64 * PITCH];
    __shared__ __align__(16) float Ys[TWO ? 64 * PITCH : 4];

    const int t = threadIdx.x;
    const int row0 = blockIdx.x * 64;

#pragma unroll
    for (int j = 0; j < 4; ++j) {
        int f4 = t + 256 * j;
        reinterpret_cast<float4*>(Ws1)[f4] = reinterpret_cast<const float4*>(Wa)[f4];
        if (TWO)
            reinterpret_cast<float4*>(Ws2)[f4] = reinterpret_cast<const float4*>(Wb)[f4];
    }
    {
        int rs = t >> 2;
        int kq = t & 3;
        int grow = row0 + rs;
#pragma unroll
        for (int j = 0; j < 4; ++j) {
            int cf4 = kq + 4 * j;
            float4 v;
            if (grow < N)
                v = *reinterpret_cast<const float4*>(io + (size_t)grow * 64 + cf4 * 4);
            else
                v = make_float4(0.f, 0.f, 0.f, 0.f);
            int kb = cf4 * 4;
            Xs[(kb + 0) * PITCH + rs] = v.x;
            Xs[(kb + 1) * PITCH + rs] = v.y;
            Xs[(kb + 2) * PITCH + rs] = v.z;
            Xs[(kb + 3) * PITCH + rs] = v.w;
        }
    }
    __syncthreads();

    const int tr = t >> 4;
    const int tc = t & 15;

    float acc[4][4];
#pragma unroll
    for (int i = 0; i < 4; ++i)
#pragma unroll
        for (int j = 0; j < 4; ++j) acc[i][j] = 0.f;

#pragma unroll 4
    for (int k = 0; k < 64; ++k) {
        float4 a = *reinterpret_cast<const float4*>(&Xs[k * PITCH + 4 * tr]);
        float4 b = *reinterpret_cast<const float4*>(&Ws1[k * 64 + 4 * tc]);
        float av[4] = {a.x, a.y, a.z, a.w};
        float bv[4] = {b.x, b.y, b.z, b.w};
#pragma unroll
        for (int i = 0; i < 4; ++i)
#pragma unroll
            for (int j = 0; j < 4; ++j) acc[i][j] = fmaf(av[i], bv[j], acc[i][j]);
    }

    float u[4][4];
#pragma unroll
    for (int i = 0; i < 4; ++i)
#pragma unroll
        for (int j = 0; j < 4; ++j)
            u[i][j] = fmaxf(acc[i][j] + ba[4 * tc + j], 0.f);

    if (TWO) {
#pragma unroll
        for (int j = 0; j < 4; ++j) {
            float4 w = make_float4(u[0][j], u[1][j], u[2][j], u[3][j]);
            *reinterpret_cast<float4*>(&Ys[(4 * tc + j) * PITCH + 4 * tr]) = w;
        }
        __syncthreads();
#pragma unroll
        for (int i = 0; i < 4; ++i)
#pragma unroll
            for (int j = 0; j < 4; ++j) acc[i][j] = 0.f;
#pragma unroll 4
        for (int k = 0; k < 64; ++k) {
            float4 a = *reinterpret_cast<const float4*>(&Ys[k * PITCH + 4 * tr]);
            float4 b = *reinterpret_cast<const float4*>(&Ws2[k * 64 + 4 * tc]);
            float av[4] = {a.x, a.y, a.z, a.w};
            float bv[4] = {b.x, b.y, b.z, b.w};
#pragma unroll
            for (int i = 0; i < 4; ++i)
#pragma unroll
                for (int j = 0; j < 4; ++j) acc[i][j] = fmaf(av[i], bv[j], acc[i][j]);
        }
#pragma unroll
        for (int i = 0; i < 4; ++i)
#pragma unroll
            for (int j = 0; j < 4; ++j)
                u[i][j] = fmaxf(acc[i][j] + bb[4 * tc + j], 0.f);
    }

    float sc[4], sh[4];
#pragma unroll
    for (int j = 0; j < 4; ++j) {
        int c = 4 * tc + j;
        float si = gi[c] * rsqrtf(vi[c] + 1e-5f);
        float ti = bei[c] - mi[c] * si;
        float so = go[c] * rsqrtf(vo[c] + 1e-5f);
        float to = beo[c] - mo[c] * so;
        sc[j] = si * so;
        sh[j] = ti * so + to;
    }
#pragma unroll
    for (int i = 0; i < 4; ++i) {
        int grow = row0 + 4 * tr + i;
        if (grow >= N) continue;
        float4 w;
        w.x = fmaxf(u[i][0] * sc[0] + sh[0], 0.f);
        w.y = fmaxf(u[i][1] * sc[1] + sh[1], 0.f);
        w.z = fmaxf(u[i][2] * sc[2] + sh[2], 0.f);
        w.w = fmaxf(u[i][3] * sc[3] + sh[3], 0.f);
        *reinterpret_cast<float4*>(io + (size_t)grow * 64 + 4 * tc) = w;
    }
}

__device__ __forceinline__ int lbound(const int* __restrict__ a, int n, int v) {
    int lo = 0, hi = n;
    while (lo < hi) {
        int mid = (lo + hi) >> 1;
        if (a[mid] < v) lo = mid + 1;
        else hi = mid;
    }
    return lo;
}

__global__ __launch_bounds__(64) void readout(
    const float* __restrict__ H, const int* __restrict__ gid, int N,
    const float* __restrict__ Wr1, const float* __restrict__ br1,
    const float* __restrict__ Wr2, const float* __restrict__ br2,
    float* __restrict__ out) {
    __shared__ __align__(16) float W1s[64 * 64];
    __shared__ __align__(16) float W2s[64 * 64];
    __shared__ float hg[64];
    __shared__ float t1[64];

    const int g = blockIdx.x;
    const int c = threadIdx.x;

    for (int j = 0; j < 64; ++j) {
        W1s[j * 64 + c] = Wr1[j * 64 + c];
        W2s[j * 64 + c] = Wr2[j * 64 + c];
    }

    int lo = lbound(gid, N, g);
    int hi = lbound(gid, N, g + 1);
    float acc = 0.f;
    for (int r = lo; r < hi; ++r) acc += H[(size_t)r * 64 + c];
    float cnt = fmaxf((float)(hi - lo), 1.0f);
    hg[c] = acc / cnt;
    __syncthreads();

    float a1 = br1[c];
    for (int k = 0; k < 64; ++k) a1 = fmaf(hg[k], W1s[k * 64 + c], a1);
    t1[c] = fmaxf(a1, 0.f);
    __syncthreads();

    float a2 = br2[c];
    for (int k = 0; k < 64; ++k) a2 = fmaf(t1[k], W2s[k * 64 + c], a2);
    out[(size_t)g * 64 + c] = a2;
}

extern "C" void kernel_launch(void* const* d_in, const int* in_sizes, int n_in,
                              void* d_out, int out_size, void* d_ws, size_t ws_size,
                              hipStream_t stream) {
    const float* x    = (const float*)d_in[0];
    const int*   src  = (const int*)d_in[1];
    const int*   dst  = (const int*)d_in[2];
    const int*   gid  = (const int*)d_in[3];
    const float* eps0 = (const float*)d_in[4];
    const float* W0a  = (const float*)d_in[5];
    const float* bb0a = (const float*)d_in[6];
    const float* W0b  = (const float*)d_in[7];
    const float* bb0b = (const float*)d_in[8];
    const float* g0i  = (const float*)d_in[9];
    const float* be0i = (const float*)d_in[10];
    const float* m0i  = (const float*)d_in[11];
    const float* v0i  = (const float*)d_in[12];
    const float* g0   = (const float*)d_in[13];
    const float* be0  = (const float*)d_in[14];
    const float* m0   = (const float*)d_in[15];
    const float* v0   = (const float*)d_in[16];
    const float* eps1 = (const float*)d_in[17];
    const float* W1a  = (const float*)d_in[18];
    const float* bb1a = (const float*)d_in[19];
    const float* g1i  = (const float*)d_in[20];
    const float* be1i = (const float*)d_in[21];
    const float* m1i  = (const float*)d_in[22];
    const float* v1i  = (const float*)d_in[23];
    const float* g1   = (const float*)d_in[24];
    const float* be1  = (const float*)d_in[25];
    const float* m1   = (const float*)d_in[26];
    const float* v1   = (const float*)d_in[27];
    const float* Wr1  = (const float*)d_in[28];
    const float* br1  = (const float*)d_in[29];
    const float* Wr2  = (const float*)d_in[30];
    const float* br2  = (const float*)d_in[31];

    const int N = in_sizes[0] / 64;       // 50000
    const int E = in_sizes[1];            // 800000
    const int G = out_size / 64 - N;      // 500
    const int NB = (N + 127) >> 7;        // buckets (<= MAXB)

    // ws layout (16-byte aligned chunks)
    char* ws = (char*)d_ws;
    float*    A       = (float*)ws;        ws += (size_t)N * 64 * 4;
    int*      row_ptr = (int*)ws;          ws += ((size_t)N + 8) * 4;
    int*      ebase   = (int*)ws;          ws += (MAXB + 4) * 4;
    int*      cursor  = (int*)ws;          ws += (MAXB + 4) * 4;
    int*      ghist   = (int*)ws;          ws += (MAXB + 4) * 4;
    unsigned* ebuf    = (unsigned*)ws;     // E u32: packed pairs, then col

    float* OUT = (float*)d_out;
    float* H   = OUT + (size_t)G * 64;

    const int EB = (E + EPB - 1) / EPB;

    // ---- build CSR (bucketed; shared by both layers) ----
    hipMemsetAsync(ghist, 0, MAXB * 4, stream);
    bucket_hist<<<EB, 256, 0, stream>>>(ghist, dst, E);
    scan_small<<<1, 1024, 0, stream>>>(ghist, ebase, cursor, NB, E);
    bin_scatter<<<EB, 256, 0, stream>>>(ebuf, cursor, src, dst, E);
    bucket_fill<<<NB, 256, 0, stream>>>(ebuf, ebase, row_ptr, N, E);

    // ---- GIN layer 0 ----
    aggregate<<<(N + 3) / 4, 256, 0, stream>>>(A, x, row_ptr, ebuf, eps0, N);
    mlp_fused<true><<<(N + 63) / 64, 256, 0, stream>>>(
        A, N, W0a, bb0a, W0b, bb0b, g0i, be0i, m0i, v0i, g0, be0, m0, v0);

    // ---- GIN layer 1 ----
    aggregate<<<(N + 3) / 4, 256, 0, stream>>>(H, A, row_ptr, ebuf, eps1, N);
    mlp_fused<false><<<(N + 63) / 64, 256, 0, stream>>>(
        H, N, W1a, bb1a, nullptr, nullptr, g1i, be1i, m1i, v1i, g1, be1, m1, v1);

    // ---- readout ----
    readout<<<G, 64, 0, stream>>>(H, gid, N, Wr1, br1, Wr2, br2, OUT);
}

// Round 5
// 173.972 us; speedup vs baseline: 8.3040x; 1.0939x over previous
//
#include <hip/hip_runtime.h>

// ---------------------------------------------------------------------------
// GIN forward via bucketed on-device CSR build + gather aggregation.
// d_out layout: [out (G*64) | h (N*64)]
// d_ws layout:  [A | row_ptr | ebase | cursor | ghist | ebuf(E u32) | hg]
// Bucket = dst >> 7 (128 nodes per bucket).  Requires N < 65536 (ids pack u16).
// ---------------------------------------------------------------------------

#define EPB 2048   // edges per block in hist/scatter
#define MAXB 512   // max buckets supported (N <= 65536)

__global__ __launch_bounds__(512) void zero_hist(int* __restrict__ gh) {
    gh[threadIdx.x] = 0;
}

// ---- Phase A: global bucket histogram (LDS-aggregated) --------------------
__global__ __launch_bounds__(256) void bucket_hist(int* __restrict__ gh,
                                                   const int* __restrict__ dst,
                                                   int E) {
    __shared__ int h[MAXB];
    const int t = threadIdx.x;
    for (int i = t; i < MAXB; i += 256) h[i] = 0;
    __syncthreads();
    const int base = blockIdx.x * EPB;
#pragma unroll
    for (int i = 0; i < 8; ++i) {
        int e = base + i * 256 + t;
        if (e < E) atomicAdd(&h[dst[e] >> 7], 1);
    }
    __syncthreads();
    for (int i = t; i < MAXB; i += 256) {
        int v = h[i];
        if (v) atomicAdd(&gh[i], v);
    }
}

// ---- Phase B: single-block scan of bucket counts -> ebase (+cursor copy) --
__global__ __launch_bounds__(1024) void scan_small(const int* __restrict__ in,
                                                   int* __restrict__ ebase,
                                                   int* __restrict__ cursor,
                                                   int n, int total) {
    __shared__ int arr[1024];
    const int t = threadIdx.x;
    int v = (t < n) ? in[t] : 0;
    arr[t] = v;
    __syncthreads();
    for (int s = 1; s < 1024; s <<= 1) {
        int u = (t >= s) ? arr[t - s] : 0;
        __syncthreads();
        arr[t] += u;
        __syncthreads();
    }
    int excl = (t > 0) ? arr[t - 1] : 0;
    if (t < n) {
        ebase[t] = excl;
        cursor[t] = excl;
    }
    if (t == 0) ebase[n] = total;
}

// ---- Phase C: scatter packed (src<<16|dst) into bucket-grouped ebuf -------
__global__ __launch_bounds__(256) void bin_scatter(unsigned* __restrict__ ebuf,
                                                   int* __restrict__ cursor,
                                                   const int* __restrict__ src,
                                                   const int* __restrict__ dst,
                                                   int E) {
    __shared__ int h[MAXB];
    __shared__ int gb[MAXB];
    const int t = threadIdx.x;
    for (int i = t; i < MAXB; i += 256) h[i] = 0;
    __syncthreads();
    const int base = blockIdx.x * EPB;
    int sv[8], dv[8];
#pragma unroll
    for (int i = 0; i < 8; ++i) {
        int e = base + i * 256 + t;
        if (e < E) {
            sv[i] = src[e];
            dv[i] = dst[e];
            atomicAdd(&h[dv[i] >> 7], 1);
        } else {
            dv[i] = -1;
        }
    }
    __syncthreads();
    for (int i = t; i < MAXB; i += 256) {
        int v = h[i];
        gb[i] = v ? atomicAdd(&cursor[i], v) : 0;
        h[i] = 0;
    }
    __syncthreads();
#pragma unroll
    for (int i = 0; i < 8; ++i) {
        if (dv[i] >= 0) {
            int b = dv[i] >> 7;
            int p = atomicAdd(&h[b], 1);
            ebuf[gb[b] + p] = ((unsigned)sv[i] << 16) | (unsigned)dv[i];
        }
    }
}

// ---- Phase D: per-bucket row_ptr + in-place col fill (LDS-staged) ---------
__global__ __launch_bounds__(256) void bucket_fill(unsigned* __restrict__ ebuf,
                                                   const int* __restrict__ ebase,
                                                   int* __restrict__ row_ptr,
                                                   int N, int E) {
    __shared__ unsigned pairLDS[4096];
    __shared__ unsigned colLDS[4096];
    __shared__ int deg[128], off[128], cur[128];
    const int b = blockIdx.x;
    const int t = threadIdx.x;
    const int lo = ebase[b];
    const int hi = ebase[b + 1];
    const int m = hi - lo;
    const int nb0 = b << 7;

    if (t < 128) deg[t] = 0;
    __syncthreads();
    for (int k = t; k < m; k += 256) {
        unsigned v = ebuf[lo + k];
        pairLDS[k] = v;
        atomicAdd(&deg[(int)(v & 0xFFFFu) - nb0], 1);
    }
    __syncthreads();
    if (t < 128) off[t] = deg[t];
    __syncthreads();
    for (int s = 1; s < 128; s <<= 1) {
        int u = 0;
        if (t < 128 && t >= s) u = off[t - s];
        __syncthreads();
        if (t < 128) off[t] += u;
        __syncthreads();
    }
    if (t < 128) {
        int excl = off[t] - deg[t];
        cur[t] = excl;
        int node = nb0 + t;
        if (node <= N) row_ptr[node] = lo + excl;
    }
    __syncthreads();
    for (int k = t; k < m; k += 256) {
        unsigned v = pairLDS[k];
        int dl = (int)(v & 0xFFFFu) - nb0;
        int p = atomicAdd(&cur[dl], 1);
        colLDS[p] = v >> 16;
    }
    __syncthreads();
    for (int k = t; k < m; k += 256) ebuf[lo + k] = colLDS[k];
    // row_ptr[N] is written by the bucket containing node N (excl==m there).
}

// ---- gather aggregation: out[n] = (1+eps)*in[n] + sum_{nbr} in[nbr] -------
__global__ __launch_bounds__(256) void aggregate(float* __restrict__ out,
                                                 const float* __restrict__ in,
                                                 const int* __restrict__ row_ptr,
                                                 const unsigned* __restrict__ col,
                                                 const float* __restrict__ eps,
                                                 int N) {
    const int n = blockIdx.x * 4 + (threadIdx.x >> 6);
    const int lane = threadIdx.x & 63;
    if (n >= N) return;
    const int lo = row_ptr[n];
    const int hi = row_ptr[n + 1];
    float acc = (1.0f + eps[0]) * in[(size_t)n * 64 + lane];
    int j = lo;
    for (; j + 4 <= hi; j += 4) {
        unsigned c0 = col[j], c1 = col[j + 1], c2 = col[j + 2], c3 = col[j + 3];
        float a0 = in[(size_t)c0 * 64 + lane];
        float a1 = in[(size_t)c1 * 64 + lane];
        float a2 = in[(size_t)c2 * 64 + lane];
        float a3 = in[(size_t)c3 * 64 + lane];
        acc += (a0 + a1) + (a2 + a3);
    }
    for (; j < hi; ++j) acc += in[(size_t)col[j] * 64 + lane];
    out[(size_t)n * 64 + lane] = acc;
}

// ---- fused GIN MLP --------------------------------------------------------
template <bool TWO>
__global__ __launch_bounds__(256) void mlp_fused(
    float* __restrict__ io, int N,
    const float* __restrict__ Wa, const float* __restrict__ ba,
    const float* __restrict__ Wb, const float* __restrict__ bb,
    const float* __restrict__ gi, const float* __restrict__ bei,
    const float* __restrict__ mi, const float* __restrict__ vi,
    const float* __restrict__ go, const float* __restrict__ beo,
    const float* __restrict__ mo, const float* __restrict__ vo) {
    constexpr int PITCH = 68;
    __shared__ __align__(16) float Ws1[64 * 64];
    __shared__ __align__(16) float Ws2[TWO ? 64 * 64 : 4];
    __shared__ __align__(16) float Xs[64 * PITCH];
    __shared__ __align__(16) float Ys[TWO ? 64 * PITCH : 4];

    const int t = threadIdx.x;
    const int row0 = blockIdx.x * 64;

#pragma unroll
    for (int j = 0; j < 4; ++j) {
        int f4 = t + 256 * j;
        reinterpret_cast<float4*>(Ws1)[f4] = reinterpret_cast<const float4*>(Wa)[f4];
        if (TWO)
            reinterpret_cast<float4*>(Ws2)[f4] = reinterpret_cast<const float4*>(Wb)[f4];
    }
    {
        int rs = t >> 2;
        int kq = t & 3;
        int grow = row0 + rs;
#pragma unroll
        for (int j = 0; j < 4; ++j) {
            int cf4 = kq + 4 * j;
            float4 v;
            if (grow < N)
                v = *reinterpret_cast<const float4*>(io + (size_t)grow * 64 + cf4 * 4);
            else
                v = make_float4(0.f, 0.f, 0.f, 0.f);
            int kb = cf4 * 4;
            Xs[(kb + 0) * PITCH + rs] = v.x;
            Xs[(kb + 1) * PITCH + rs] = v.y;
            Xs[(kb + 2) * PITCH + rs] = v.z;
            Xs[(kb + 3) * PITCH + rs] = v.w;
        }
    }
    __syncthreads();

    const int tr = t >> 4;
    const int tc = t & 15;

    float acc[4][4];
#pragma unroll
    for (int i = 0; i < 4; ++i)
#pragma unroll
        for (int j = 0; j < 4; ++j) acc[i][j] = 0.f;

#pragma unroll 4
    for (int k = 0; k < 64; ++k) {
        float4 a = *reinterpret_cast<const float4*>(&Xs[k * PITCH + 4 * tr]);
        float4 b = *reinterpret_cast<const float4*>(&Ws1[k * 64 + 4 * tc]);
        float av[4] = {a.x, a.y, a.z, a.w};
        float bv[4] = {b.x, b.y, b.z, b.w};
#pragma unroll
        for (int i = 0; i < 4; ++i)
#pragma unroll
            for (int j = 0; j < 4; ++j) acc[i][j] = fmaf(av[i], bv[j], acc[i][j]);
    }

    float u[4][4];
#pragma unroll
    for (int i = 0; i < 4; ++i)
#pragma unroll
        for (int j = 0; j < 4; ++j)
            u[i][j] = fmaxf(acc[i][j] + ba[4 * tc + j], 0.f);

    if (TWO) {
#pragma unroll
        for (int j = 0; j < 4; ++j) {
            float4 w = make_float4(u[0][j], u[1][j], u[2][j], u[3][j]);
            *reinterpret_cast<float4*>(&Ys[(4 * tc + j) * PITCH + 4 * tr]) = w;
        }
        __syncthreads();
#pragma unroll
        for (int i = 0; i < 4; ++i)
#pragma unroll
            for (int j = 0; j < 4; ++j) acc[i][j] = 0.f;
#pragma unroll 4
        for (int k = 0; k < 64; ++k) {
            float4 a = *reinterpret_cast<const float4*>(&Ys[k * PITCH + 4 * tr]);
            float4 b = *reinterpret_cast<const float4*>(&Ws2[k * 64 + 4 * tc]);
            float av[4] = {a.x, a.y, a.z, a.w};
            float bv[4] = {b.x, b.y, b.z, b.w};
#pragma unroll
            for (int i = 0; i < 4; ++i)
#pragma unroll
                for (int j = 0; j < 4; ++j) acc[i][j] = fmaf(av[i], bv[j], acc[i][j]);
        }
#pragma unroll
        for (int i = 0; i < 4; ++i)
#pragma unroll
            for (int j = 0; j < 4; ++j)
                u[i][j] = fmaxf(acc[i][j] + bb[4 * tc + j], 0.f);
    }

    float sc[4], sh[4];
#pragma unroll
    for (int j = 0; j < 4; ++j) {
        int c = 4 * tc + j;
        float si = gi[c] * rsqrtf(vi[c] + 1e-5f);
        float ti = bei[c] - mi[c] * si;
        float so = go[c] * rsqrtf(vo[c] + 1e-5f);
        float to = beo[c] - mo[c] * so;
        sc[j] = si * so;
        sh[j] = ti * so + to;
    }
#pragma unroll
    for (int i = 0; i < 4; ++i) {
        int grow = row0 + 4 * tr + i;
        if (grow >= N) continue;
        float4 w;
        w.x = fmaxf(u[i][0] * sc[0] + sh[0], 0.f);
        w.y = fmaxf(u[i][1] * sc[1] + sh[1], 0.f);
        w.z = fmaxf(u[i][2] * sc[2] + sh[2], 0.f);
        w.w = fmaxf(u[i][3] * sc[3] + sh[3], 0.f);
        *reinterpret_cast<float4*>(io + (size_t)grow * 64 + 4 * tc) = w;
    }
}

__device__ __forceinline__ int lbound(const int* __restrict__ a, int n, int v) {
    int lo = 0, hi = n;
    while (lo < hi) {
        int mid = (lo + hi) >> 1;
        if (a[mid] < v) lo = mid + 1;
        else hi = mid;
    }
    return lo;
}

// ---- per-graph mean: hg[g][c] = mean over rows of H ----------------------
__global__ __launch_bounds__(256) void graph_mean(const float* __restrict__ H,
                                                  const int* __restrict__ gid,
                                                  int N,
                                                  float* __restrict__ hg) {
    __shared__ float part[4][64];
    const int g = blockIdx.x;
    const int lane = threadIdx.x & 63;
    const int w = threadIdx.x >> 6;
    const int lo = lbound(gid, N, g);
    const int hi = lbound(gid, N, g + 1);
    float acc = 0.f;
    for (int r = lo + w; r < hi; r += 4) acc += H[(size_t)r * 64 + lane];
    part[w][lane] = acc;
    __syncthreads();
    if (w == 0) {
        float s = part[0][lane] + part[1][lane] + part[2][lane] + part[3][lane];
        float cnt = fmaxf((float)(hi - lo), 1.0f);
        hg[(size_t)g * 64 + lane] = s / cnt;
    }
}

// ---- readout MLP: out = relu(hg@W1+b1)@W2+b2, 64 graphs per block --------
__global__ __launch_bounds__(256) void readout_mlp(
    const float* __restrict__ hg, int G,
    const float* __restrict__ W1, const float* __restrict__ b1,
    const float* __restrict__ W2, const float* __restrict__ b2,
    float* __restrict__ out) {
    constexpr int PITCH = 68;
    __shared__ __align__(16) float Ws1[64 * 64];
    __shared__ __align__(16) float Ws2[64 * 64];
    __shared__ __align__(16) float Xs[64 * PITCH];
    __shared__ __align__(16) float Ys[64 * PITCH];

    const int t = threadIdx.x;
    const int row0 = blockIdx.x * 64;

#pragma unroll
    for (int j = 0; j < 4; ++j) {
        int f4 = t + 256 * j;
        reinterpret_cast<float4*>(Ws1)[f4] = reinterpret_cast<const float4*>(W1)[f4];
        reinterpret_cast<float4*>(Ws2)[f4] = reinterpret_cast<const float4*>(W2)[f4];
    }
    {
        int rs = t >> 2;
        int kq = t & 3;
        int grow = row0 + rs;
#pragma unroll
        for (int j = 0; j < 4; ++j) {
            int cf4 = kq + 4 * j;
            float4 v = make_float4(0.f, 0.f, 0.f, 0.f);
            if (grow < G)
                v = *reinterpret_cast<const float4*>(hg + (size_t)grow * 64 + cf4 * 4);
            int kb = cf4 * 4;
            Xs[(kb + 0) * PITCH + rs] = v.x;
            Xs[(kb + 1) * PITCH + rs] = v.y;
            Xs[(kb + 2) * PITCH + rs] = v.z;
            Xs[(kb + 3) * PITCH + rs] = v.w;
        }
    }
    __syncthreads();

    const int tr = t >> 4;
    const int tc = t & 15;

    float acc[4][4];
#pragma unroll
    for (int i = 0; i < 4; ++i)
#pragma unroll
        for (int j = 0; j < 4; ++j) acc[i][j] = 0.f;
#pragma unroll 4
    for (int k = 0; k < 64; ++k) {
        float4 a = *reinterpret_cast<const float4*>(&Xs[k * PITCH + 4 * tr]);
        float4 b = *reinterpret_cast<const float4*>(&Ws1[k * 64 + 4 * tc]);
        float av[4] = {a.x, a.y, a.z, a.w};
        float bv[4] = {b.x, b.y, b.z, b.w};
#pragma unroll
        for (int i = 0; i < 4; ++i)
#pragma unroll
            for (int j = 0; j < 4; ++j) acc[i][j] = fmaf(av[i], bv[j], acc[i][j]);
    }
    float u[4][4];
#pragma unroll
    for (int i = 0; i < 4; ++i)
#pragma unroll
        for (int j = 0; j < 4; ++j)
            u[i][j] = fmaxf(acc[i][j] + b1[4 * tc + j], 0.f);

#pragma unroll
    for (int j = 0; j < 4; ++j) {
        float4 w = make_float4(u[0][j], u[1][j], u[2][j], u[3][j]);
        *reinterpret_cast<float4*>(&Ys[(4 * tc + j) * PITCH + 4 * tr]) = w;
    }
    __syncthreads();
#pragma unroll
    for (int i = 0; i < 4; ++i)
#pragma unroll
        for (int j = 0; j < 4; ++j) acc[i][j] = 0.f;
#pragma unroll 4
    for (int k = 0; k < 64; ++k) {
        float4 a = *reinterpret_cast<const float4*>(&Ys[k * PITCH + 4 * tr]);
        float4 b = *reinterpret_cast<const float4*>(&Ws2[k * 64 + 4 * tc]);
        float av[4] = {a.x, a.y, a.z, a.w};
        float bv[4] = {b.x, b.y, b.z, b.w};
#pragma unroll
        for (int i = 0; i < 4; ++i)
#pragma unroll
            for (int j = 0; j < 4; ++j) acc[i][j] = fmaf(av[i], bv[j], acc[i][j]);
    }
#pragma unroll
    for (int i = 0; i < 4; ++i) {
        int grow = row0 + 4 * tr + i;
        if (grow >= G) continue;
        float4 w;
        w.x = acc[i][0] + b2[4 * tc + 0];
        w.y = acc[i][1] + b2[4 * tc + 1];
        w.z = acc[i][2] + b2[4 * tc + 2];
        w.w = acc[i][3] + b2[4 * tc + 3];
        *reinterpret_cast<float4*>(out + (size_t)grow * 64 + 4 * tc) = w;
    }
}

extern "C" void kernel_launch(void* const* d_in, const int* in_sizes, int n_in,
                              void* d_out, int out_size, void* d_ws, size_t ws_size,
                              hipStream_t stream) {
    const float* x    = (const float*)d_in[0];
    const int*   src  = (const int*)d_in[1];
    const int*   dst  = (const int*)d_in[2];
    const int*   gid  = (const int*)d_in[3];
    const float* eps0 = (const float*)d_in[4];
    const float* W0a  = (const float*)d_in[5];
    const float* bb0a = (const float*)d_in[6];
    const float* W0b  = (const float*)d_in[7];
    const float* bb0b = (const float*)d_in[8];
    const float* g0i  = (const float*)d_in[9];
    const float* be0i = (const float*)d_in[10];
    const float* m0i  = (const float*)d_in[11];
    const float* v0i  = (const float*)d_in[12];
    const float* g0   = (const float*)d_in[13];
    const float* be0  = (const float*)d_in[14];
    const float* m0   = (const float*)d_in[15];
    const float* v0   = (const float*)d_in[16];
    const float* eps1 = (const float*)d_in[17];
    const float* W1a  = (const float*)d_in[18];
    const float* bb1a = (const float*)d_in[19];
    const float* g1i  = (const float*)d_in[20];
    const float* be1i = (const float*)d_in[21];
    const float* m1i  = (const float*)d_in[22];
    const float* v1i  = (const float*)d_in[23];
    const float* g1   = (const float*)d_in[24];
    const float* be1  = (const float*)d_in[25];
    const float* m1   = (const float*)d_in[26];
    const float* v1   = (const float*)d_in[27];
    const float* Wr1  = (const float*)d_in[28];
    const float* br1  = (const float*)d_in[29];
    const float* Wr2  = (const float*)d_in[30];
    const float* br2  = (const float*)d_in[31];

    const int N = in_sizes[0] / 64;       // 50000
    const int E = in_sizes[1];            // 800000
    const int G = out_size / 64 - N;      // 500
    const int NB = (N + 127) >> 7;        // buckets (<= MAXB)

    // ws layout (16-byte aligned chunks)
    char* ws = (char*)d_ws;
    float*    A       = (float*)ws;        ws += (size_t)N * 64 * 4;
    int*      row_ptr = (int*)ws;          ws += ((size_t)N + 8) * 4;
    int*      ebase   = (int*)ws;          ws += (MAXB + 4) * 4;
    int*      cursor  = (int*)ws;          ws += (MAXB + 4) * 4;
    int*      ghist   = (int*)ws;          ws += (MAXB + 4) * 4;
    unsigned* ebuf    = (unsigned*)ws;     ws += (size_t)E * 4;
    float*    hg      = (float*)ws;        // G*64

    float* OUT = (float*)d_out;
    float* H   = OUT + (size_t)G * 64;

    const int EB = (E + EPB - 1) / EPB;

    // ---- build CSR (bucketed; shared by both layers) ----
    zero_hist<<<1, MAXB, 0, stream>>>(ghist);
    bucket_hist<<<EB, 256, 0, stream>>>(ghist, dst, E);
    scan_small<<<1, 1024, 0, stream>>>(ghist, ebase, cursor, NB, E);
    bin_scatter<<<EB, 256, 0, stream>>>(ebuf, cursor, src, dst, E);
    bucket_fill<<<NB, 256, 0, stream>>>(ebuf, ebase, row_ptr, N, E);

    // ---- GIN layer 0 ----
    aggregate<<<(N + 3) / 4, 256, 0, stream>>>(A, x, row_ptr, ebuf, eps0, N);
    mlp_fused<true><<<(N + 63) / 64, 256, 0, stream>>>(
        A, N, W0a, bb0a, W0b, bb0b, g0i, be0i, m0i, v0i, g0, be0, m0, v0);

    // ---- GIN layer 1 ----
    aggregate<<<(N + 3) / 4, 256, 0, stream>>>(H, A, row_ptr, ebuf, eps1, N);
    mlp_fused<false><<<(N + 63) / 64, 256, 0, stream>>>(
        H, N, W1a, bb1a, nullptr, nullptr, g1i, be1i, m1i, v1i, g1, be1, m1, v1);

    // ---- readout ----
    graph_mean<<<G, 256, 0, stream>>>(H, gid, N, hg);
    readout_mlp<<<(G + 63) / 64, 256, 0, stream>>>(hg, G, Wr1, br1, Wr2, br2, OUT);
}

// Round 6
// 167.726 us; speedup vs baseline: 8.6132x; 1.0372x over previous
//
#include <hip/hip_runtime.h>

// ---------------------------------------------------------------------------
// GIN forward via bucketed on-device CSR build + gather aggregation.
// d_out layout: [out (G*64) | h (N*64)]
// d_ws layout:  [A | row_ptr | ebase | cursor | ghist | ebuf(E u32) | hg]
// Bucket = dst >> 7 (128 nodes per bucket).  Requires N < 65536 (ids pack u16).
// ---------------------------------------------------------------------------

#define EPB 2048   // edges per block in hist/scatter
#define MAXB 512   // max buckets supported (N <= 65536)

__global__ __launch_bounds__(512) void zero_hist(int* __restrict__ gh) {
    gh[threadIdx.x] = 0;
}

// ---- Phase A: global bucket histogram (LDS-aggregated) --------------------
__global__ __launch_bounds__(256) void bucket_hist(int* __restrict__ gh,
                                                   const int* __restrict__ dst,
                                                   int E) {
    __shared__ int h[MAXB];
    const int t = threadIdx.x;
    for (int i = t; i < MAXB; i += 256) h[i] = 0;
    __syncthreads();
    const int base = blockIdx.x * EPB;
#pragma unroll
    for (int i = 0; i < 8; ++i) {
        int e = base + i * 256 + t;
        if (e < E) atomicAdd(&h[dst[e] >> 7], 1);
    }
    __syncthreads();
    for (int i = t; i < MAXB; i += 256) {
        int v = h[i];
        if (v) atomicAdd(&gh[i], v);
    }
}

// ---- Phase B: single-block scan of bucket counts -> ebase (+cursor copy) --
__global__ __launch_bounds__(1024) void scan_small(const int* __restrict__ in,
                                                   int* __restrict__ ebase,
                                                   int* __restrict__ cursor,
                                                   int n, int total) {
    __shared__ int arr[1024];
    const int t = threadIdx.x;
    int v = (t < n) ? in[t] : 0;
    arr[t] = v;
    __syncthreads();
    for (int s = 1; s < 1024; s <<= 1) {
        int u = (t >= s) ? arr[t - s] : 0;
        __syncthreads();
        arr[t] += u;
        __syncthreads();
    }
    int excl = (t > 0) ? arr[t - 1] : 0;
    if (t < n) {
        ebase[t] = excl;
        cursor[t] = excl;
    }
    if (t == 0) ebase[n] = total;
}

// ---- Phase C: scatter packed (src<<16|dst) into bucket-grouped ebuf -------
__global__ __launch_bounds__(256) void bin_scatter(unsigned* __restrict__ ebuf,
                                                   int* __restrict__ cursor,
                                                   const int* __restrict__ src,
                                                   const int* __restrict__ dst,
                                                   int E) {
    __shared__ int h[MAXB];
    __shared__ int gb[MAXB];
    const int t = threadIdx.x;
    for (int i = t; i < MAXB; i += 256) h[i] = 0;
    __syncthreads();
    const int base = blockIdx.x * EPB;
    int sv[8], dv[8];
#pragma unroll
    for (int i = 0; i < 8; ++i) {
        int e = base + i * 256 + t;
        if (e < E) {
            sv[i] = src[e];
            dv[i] = dst[e];
            atomicAdd(&h[dv[i] >> 7], 1);
        } else {
            dv[i] = -1;
        }
    }
    __syncthreads();
    for (int i = t; i < MAXB; i += 256) {
        int v = h[i];
        gb[i] = v ? atomicAdd(&cursor[i], v) : 0;
        h[i] = 0;
    }
    __syncthreads();
#pragma unroll
    for (int i = 0; i < 8; ++i) {
        if (dv[i] >= 0) {
            int b = dv[i] >> 7;
            int p = atomicAdd(&h[b], 1);
            ebuf[gb[b] + p] = ((unsigned)sv[i] << 16) | (unsigned)dv[i];
        }
    }
}

// ---- Phase D: per-bucket row_ptr + in-place col fill (LDS-staged) ---------
__global__ __launch_bounds__(256) void bucket_fill(unsigned* __restrict__ ebuf,
                                                   const int* __restrict__ ebase,
                                                   int* __restrict__ row_ptr,
                                                   int N, int E) {
    __shared__ unsigned pairLDS[4096];
    __shared__ unsigned colLDS[4096];
    __shared__ int deg[128], off[128], cur[128];
    const int b = blockIdx.x;
    const int t = threadIdx.x;
    const int lo = ebase[b];
    const int hi = ebase[b + 1];
    const int m = hi - lo;
    const int nb0 = b << 7;

    if (t < 128) deg[t] = 0;
    __syncthreads();
    for (int k = t; k < m; k += 256) {
        unsigned v = ebuf[lo + k];
        pairLDS[k] = v;
        atomicAdd(&deg[(int)(v & 0xFFFFu) - nb0], 1);
    }
    __syncthreads();
    if (t < 128) off[t] = deg[t];
    __syncthreads();
    for (int s = 1; s < 128; s <<= 1) {
        int u = 0;
        if (t < 128 && t >= s) u = off[t - s];
        __syncthreads();
        if (t < 128) off[t] += u;
        __syncthreads();
    }
    if (t < 128) {
        int excl = off[t] - deg[t];
        cur[t] = excl;
        int node = nb0 + t;
        if (node <= N) row_ptr[node] = lo + excl;
    }
    __syncthreads();
    for (int k = t; k < m; k += 256) {
        unsigned v = pairLDS[k];
        int dl = (int)(v & 0xFFFFu) - nb0;
        int p = atomicAdd(&cur[dl], 1);
        colLDS[p] = v >> 16;
    }
    __syncthreads();
    for (int k = t; k < m; k += 256) ebuf[lo + k] = colLDS[k];
    // row_ptr[N] is written by the bucket containing node N (excl==m there).
}

// ---- gather aggregation: out[n] = (1+eps)*in[n] + sum_{nbr} in[nbr] -------
// One wave per node. lane = (jj = neighbor slot 0..3, q = float4 slot 0..15):
// 4 neighbors in flight per iteration, 16B/lane loads, shfl-reduce at end.
__global__ __launch_bounds__(256) void aggregate(float* __restrict__ out,
                                                 const float* __restrict__ in,
                                                 const int* __restrict__ row_ptr,
                                                 const unsigned* __restrict__ col,
                                                 const float* __restrict__ eps,
                                                 int N) {
    const int n = blockIdx.x * 4 + (threadIdx.x >> 6);
    if (n >= N) return;
    const int lane = threadIdx.x & 63;
    const int q = lane & 15;   // float4 index within the 64-float row
    const int jj = lane >> 4;  // neighbor slot

    const int lo = row_ptr[n];
    const int hi = row_ptr[n + 1];

    float ax = 0.f, ay = 0.f, az = 0.f, aw = 0.f;
    int j = lo;
#pragma unroll 2
    for (; j + 4 <= hi; j += 4) {
        unsigned c = col[j + jj];
        float4 v = *reinterpret_cast<const float4*>(in + (size_t)c * 64 + q * 4);
        ax += v.x; ay += v.y; az += v.z; aw += v.w;
    }
    if (j + jj < hi) {
        unsigned c = col[j + jj];
        float4 v = *reinterpret_cast<const float4*>(in + (size_t)c * 64 + q * 4);
        ax += v.x; ay += v.y; az += v.z; aw += v.w;
    }

    // reduce the 4 neighbor slots (lanes differing in bits 4,5)
    ax += __shfl_xor(ax, 16); ay += __shfl_xor(ay, 16);
    az += __shfl_xor(az, 16); aw += __shfl_xor(aw, 16);
    ax += __shfl_xor(ax, 32); ay += __shfl_xor(ay, 32);
    az += __shfl_xor(az, 32); aw += __shfl_xor(aw, 32);

    if (jj == 0) {
        float s = 1.0f + eps[0];
        float4 own = *reinterpret_cast<const float4*>(in + (size_t)n * 64 + q * 4);
        float4 w;
        w.x = fmaf(s, own.x, ax);
        w.y = fmaf(s, own.y, ay);
        w.z = fmaf(s, own.z, az);
        w.w = fmaf(s, own.w, aw);
        *reinterpret_cast<float4*>(out + (size_t)n * 64 + q * 4) = w;
    }
}

// ---- fused GIN MLP --------------------------------------------------------
template <bool TWO>
__global__ __launch_bounds__(256) void mlp_fused(
    float* __restrict__ io, int N,
    const float* __restrict__ Wa, const float* __restrict__ ba,
    const float* __restrict__ Wb, const float* __restrict__ bb,
    const float* __restrict__ gi, const float* __restrict__ bei,
    const float* __restrict__ mi, const float* __restrict__ vi,
    const float* __restrict__ go, const float* __restrict__ beo,
    const float* __restrict__ mo, const float* __restrict__ vo) {
    constexpr int PITCH = 68;
    __shared__ __align__(16) float Ws1[64 * 64];
    __shared__ __align__(16) float Ws2[TWO ? 64 * 64 : 4];
    __shared__ __align__(16) float Xs[64 * PITCH];
    __shared__ __align__(16) float Ys[TWO ? 64 * PITCH : 4];

    const int t = threadIdx.x;
    const int row0 = blockIdx.x * 64;

#pragma unroll
    for (int j = 0; j < 4; ++j) {
        int f4 = t + 256 * j;
        reinterpret_cast<float4*>(Ws1)[f4] = reinterpret_cast<const float4*>(Wa)[f4];
        if (TWO)
            reinterpret_cast<float4*>(Ws2)[f4] = reinterpret_cast<const float4*>(Wb)[f4];
    }
    {
        int rs = t >> 2;
        int kq = t & 3;
        int grow = row0 + rs;
#pragma unroll
        for (int j = 0; j < 4; ++j) {
            int cf4 = kq + 4 * j;
            float4 v;
            if (grow < N)
                v = *reinterpret_cast<const float4*>(io + (size_t)grow * 64 + cf4 * 4);
            else
                v = make_float4(0.f, 0.f, 0.f, 0.f);
            int kb = cf4 * 4;
            Xs[(kb + 0) * PITCH + rs] = v.x;
            Xs[(kb + 1) * PITCH + rs] = v.y;
            Xs[(kb + 2) * PITCH + rs] = v.z;
            Xs[(kb + 3) * PITCH + rs] = v.w;
        }
    }
    __syncthreads();

    const int tr = t >> 4;
    const int tc = t & 15;

    float acc[4][4];
#pragma unroll
    for (int i = 0; i < 4; ++i)
#pragma unroll
        for (int j = 0; j < 4; ++j) acc[i][j] = 0.f;

#pragma unroll 4
    for (int k = 0; k < 64; ++k) {
        float4 a = *reinterpret_cast<const float4*>(&Xs[k * PITCH + 4 * tr]);
        float4 b = *reinterpret_cast<const float4*>(&Ws1[k * 64 + 4 * tc]);
        float av[4] = {a.x, a.y, a.z, a.w};
        float bv[4] = {b.x, b.y, b.z, b.w};
#pragma unroll
        for (int i = 0; i < 4; ++i)
#pragma unroll
            for (int j = 0; j < 4; ++j) acc[i][j] = fmaf(av[i], bv[j], acc[i][j]);
    }

    float u[4][4];
#pragma unroll
    for (int i = 0; i < 4; ++i)
#pragma unroll
        for (int j = 0; j < 4; ++j)
            u[i][j] = fmaxf(acc[i][j] + ba[4 * tc + j], 0.f);

    if (TWO) {
#pragma unroll
        for (int j = 0; j < 4; ++j) {
            float4 w = make_float4(u[0][j], u[1][j], u[2][j], u[3][j]);
            *reinterpret_cast<float4*>(&Ys[(4 * tc + j) * PITCH + 4 * tr]) = w;
        }
        __syncthreads();
#pragma unroll
        for (int i = 0; i < 4; ++i)
#pragma unroll
            for (int j = 0; j < 4; ++j) acc[i][j] = 0.f;
#pragma unroll 4
        for (int k = 0; k < 64; ++k) {
            float4 a = *reinterpret_cast<const float4*>(&Ys[k * PITCH + 4 * tr]);
            float4 b = *reinterpret_cast<const float4*>(&Ws2[k * 64 + 4 * tc]);
            float av[4] = {a.x, a.y, a.z, a.w};
            float bv[4] = {b.x, b.y, b.z, b.w};
#pragma unroll
            for (int i = 0; i < 4; ++i)
#pragma unroll
                for (int j = 0; j < 4; ++j) acc[i][j] = fmaf(av[i], bv[j], acc[i][j]);
        }
#pragma unroll
        for (int i = 0; i < 4; ++i)
#pragma unroll
            for (int j = 0; j < 4; ++j)
                u[i][j] = fmaxf(acc[i][j] + bb[4 * tc + j], 0.f);
    }

    float sc[4], sh[4];
#pragma unroll
    for (int j = 0; j < 4; ++j) {
        int c = 4 * tc + j;
        float si = gi[c] * rsqrtf(vi[c] + 1e-5f);
        float ti = bei[c] - mi[c] * si;
        float so = go[c] * rsqrtf(vo[c] + 1e-5f);
        float to = beo[c] - mo[c] * so;
        sc[j] = si * so;
        sh[j] = ti * so + to;
    }
#pragma unroll
    for (int i = 0; i < 4; ++i) {
        int grow = row0 + 4 * tr + i;
        if (grow >= N) continue;
        float4 w;
        w.x = fmaxf(u[i][0] * sc[0] + sh[0], 0.f);
        w.y = fmaxf(u[i][1] * sc[1] + sh[1], 0.f);
        w.z = fmaxf(u[i][2] * sc[2] + sh[2], 0.f);
        w.w = fmaxf(u[i][3] * sc[3] + sh[3], 0.f);
        *reinterpret_cast<float4*>(io + (size_t)grow * 64 + 4 * tc) = w;
    }
}

__device__ __forceinline__ int lbound(const int* __restrict__ a, int n, int v) {
    int lo = 0, hi = n;
    while (lo < hi) {
        int mid = (lo + hi) >> 1;
        if (a[mid] < v) lo = mid + 1;
        else hi = mid;
    }
    return lo;
}

// ---- per-graph mean: hg[g][c] = mean over rows of H ----------------------
__global__ __launch_bounds__(256) void graph_mean(const float* __restrict__ H,
                                                  const int* __restrict__ gid,
                                                  int N,
                                                  float* __restrict__ hg) {
    __shared__ float part[4][64];
    const int g = blockIdx.x;
    const int lane = threadIdx.x & 63;
    const int w = threadIdx.x >> 6;
    const int lo = lbound(gid, N, g);
    const int hi = lbound(gid, N, g + 1);
    float acc = 0.f;
    for (int r = lo + w; r < hi; r += 4) acc += H[(size_t)r * 64 + lane];
    part[w][lane] = acc;
    __syncthreads();
    if (w == 0) {
        float s = part[0][lane] + part[1][lane] + part[2][lane] + part[3][lane];
        float cnt = fmaxf((float)(hi - lo), 1.0f);
        hg[(size_t)g * 64 + lane] = s / cnt;
    }
}

// ---- readout MLP: out = relu(hg@W1+b1)@W2+b2, 64 graphs per block --------
__global__ __launch_bounds__(256) void readout_mlp(
    const float* __restrict__ hg, int G,
    const float* __restrict__ W1, const float* __restrict__ b1,
    const float* __restrict__ W2, const float* __restrict__ b2,
    float* __restrict__ out) {
    constexpr int PITCH = 68;
    __shared__ __align__(16) float Ws1[64 * 64];
    __shared__ __align__(16) float Ws2[64 * 64];
    __shared__ __align__(16) float Xs[64 * PITCH];
    __shared__ __align__(16) float Ys[64 * PITCH];

    const int t = threadIdx.x;
    const int row0 = blockIdx.x * 64;

#pragma unroll
    for (int j = 0; j < 4; ++j) {
        int f4 = t + 256 * j;
        reinterpret_cast<float4*>(Ws1)[f4] = reinterpret_cast<const float4*>(W1)[f4];
        reinterpret_cast<float4*>(Ws2)[f4] = reinterpret_cast<const float4*>(W2)[f4];
    }
    {
        int rs = t >> 2;
        int kq = t & 3;
        int grow = row0 + rs;
#pragma unroll
        for (int j = 0; j < 4; ++j) {
            int cf4 = kq + 4 * j;
            float4 v = make_float4(0.f, 0.f, 0.f, 0.f);
            if (grow < G)
                v = *reinterpret_cast<const float4*>(hg + (size_t)grow * 64 + cf4 * 4);
            int kb = cf4 * 4;
            Xs[(kb + 0) * PITCH + rs] = v.x;
            Xs[(kb + 1) * PITCH + rs] = v.y;
            Xs[(kb + 2) * PITCH + rs] = v.z;
            Xs[(kb + 3) * PITCH + rs] = v.w;
        }
    }
    __syncthreads();

    const int tr = t >> 4;
    const int tc = t & 15;

    float acc[4][4];
#pragma unroll
    for (int i = 0; i < 4; ++i)
#pragma unroll
        for (int j = 0; j < 4; ++j) acc[i][j] = 0.f;
#pragma unroll 4
    for (int k = 0; k < 64; ++k) {
        float4 a = *reinterpret_cast<const float4*>(&Xs[k * PITCH + 4 * tr]);
        float4 b = *reinterpret_cast<const float4*>(&Ws1[k * 64 + 4 * tc]);
        float av[4] = {a.x, a.y, a.z, a.w};
        float bv[4] = {b.x, b.y, b.z, b.w};
#pragma unroll
        for (int i = 0; i < 4; ++i)
#pragma unroll
            for (int j = 0; j < 4; ++j) acc[i][j] = fmaf(av[i], bv[j], acc[i][j]);
    }
    float u[4][4];
#pragma unroll
    for (int i = 0; i < 4; ++i)
#pragma unroll
        for (int j = 0; j < 4; ++j)
            u[i][j] = fmaxf(acc[i][j] + b1[4 * tc + j], 0.f);

#pragma unroll
    for (int j = 0; j < 4; ++j) {
        float4 w = make_float4(u[0][j], u[1][j], u[2][j], u[3][j]);
        *reinterpret_cast<float4*>(&Ys[(4 * tc + j) * PITCH + 4 * tr]) = w;
    }
    __syncthreads();
#pragma unroll
    for (int i = 0; i < 4; ++i)
#pragma unroll
        for (int j = 0; j < 4; ++j) acc[i][j] = 0.f;
#pragma unroll 4
    for (int k = 0; k < 64; ++k) {
        float4 a = *reinterpret_cast<const float4*>(&Ys[k * PITCH + 4 * tr]);
        float4 b = *reinterpret_cast<const float4*>(&Ws2[k * 64 + 4 * tc]);
        float av[4] = {a.x, a.y, a.z, a.w};
        float bv[4] = {b.x, b.y, b.z, b.w};
#pragma unroll
        for (int i = 0; i < 4; ++i)
#pragma unroll
            for (int j = 0; j < 4; ++j) acc[i][j] = fmaf(av[i], bv[j], acc[i][j]);
    }
#pragma unroll
    for (int i = 0; i < 4; ++i) {
        int grow = row0 + 4 * tr + i;
        if (grow >= G) continue;
        float4 w;
        w.x = acc[i][0] + b2[4 * tc + 0];
        w.y = acc[i][1] + b2[4 * tc + 1];
        w.z = acc[i][2] + b2[4 * tc + 2];
        w.w = acc[i][3] + b2[4 * tc + 3];
        *reinterpret_cast<float4*>(out + (size_t)grow * 64 + 4 * tc) = w;
    }
}

extern "C" void kernel_launch(void* const* d_in, const int* in_sizes, int n_in,
                              void* d_out, int out_size, void* d_ws, size_t ws_size,
                              hipStream_t stream) {
    const float* x    = (const float*)d_in[0];
    const int*   src  = (const int*)d_in[1];
    const int*   dst  = (const int*)d_in[2];
    const int*   gid  = (const int*)d_in[3];
    const float* eps0 = (const float*)d_in[4];
    const float* W0a  = (const float*)d_in[5];
    const float* bb0a = (const float*)d_in[6];
    const float* W0b  = (const float*)d_in[7];
    const float* bb0b = (const float*)d_in[8];
    const float* g0i  = (const float*)d_in[9];
    const float* be0i = (const float*)d_in[10];
    const float* m0i  = (const float*)d_in[11];
    const float* v0i  = (const float*)d_in[12];
    const float* g0   = (const float*)d_in[13];
    const float* be0  = (const float*)d_in[14];
    const float* m0   = (const float*)d_in[15];
    const float* v0   = (const float*)d_in[16];
    const float* eps1 = (const float*)d_in[17];
    const float* W1a  = (const float*)d_in[18];
    const float* bb1a = (const float*)d_in[19];
    const float* g1i  = (const float*)d_in[20];
    const float* be1i = (const float*)d_in[21];
    const float* m1i  = (const float*)d_in[22];
    const float* v1i  = (const float*)d_in[23];
    const float* g1   = (const float*)d_in[24];
    const float* be1  = (const float*)d_in[25];
    const float* m1   = (const float*)d_in[26];
    const float* v1   = (const float*)d_in[27];
    const float* Wr1  = (const float*)d_in[28];
    const float* br1  = (const float*)d_in[29];
    const float* Wr2  = (const float*)d_in[30];
    const float* br2  = (const float*)d_in[31];

    const int N = in_sizes[0] / 64;       // 50000
    const int E = in_sizes[1];            // 800000
    const int G = out_size / 64 - N;      // 500
    const int NB = (N + 127) >> 7;        // buckets (<= MAXB)

    // ws layout (16-byte aligned chunks)
    char* ws = (char*)d_ws;
    float*    A       = (float*)ws;        ws += (size_t)N * 64 * 4;
    int*      row_ptr = (int*)ws;          ws += ((size_t)N + 8) * 4;
    int*      ebase   = (int*)ws;          ws += (MAXB + 4) * 4;
    int*      cursor  = (int*)ws;          ws += (MAXB + 4) * 4;
    int*      ghist   = (int*)ws;          ws += (MAXB + 4) * 4;
    unsigned* ebuf    = (unsigned*)ws;     ws += (size_t)E * 4;
    float*    hg      = (float*)ws;        // G*64

    float* OUT = (float*)d_out;
    float* H   = OUT + (size_t)G * 64;

    const int EB = (E + EPB - 1) / EPB;

    // ---- build CSR (bucketed; shared by both layers) ----
    zero_hist<<<1, MAXB, 0, stream>>>(ghist);
    bucket_hist<<<EB, 256, 0, stream>>>(ghist, dst, E);
    scan_small<<<1, 1024, 0, stream>>>(ghist, ebase, cursor, NB, E);
    bin_scatter<<<EB, 256, 0, stream>>>(ebuf, cursor, src, dst, E);
    bucket_fill<<<NB, 256, 0, stream>>>(ebuf, ebase, row_ptr, N, E);

    // ---- GIN layer 0 ----
    aggregate<<<(N + 3) / 4, 256, 0, stream>>>(A, x, row_ptr, ebuf, eps0, N);
    mlp_fused<true><<<(N + 63) / 64, 256, 0, stream>>>(
        A, N, W0a, bb0a, W0b, bb0b, g0i, be0i, m0i, v0i, g0, be0, m0, v0);

    // ---- GIN layer 1 ----
    aggregate<<<(N + 3) / 4, 256, 0, stream>>>(H, A, row_ptr, ebuf, eps1, N);
    mlp_fused<false><<<(N + 63) / 64, 256, 0, stream>>>(
        H, N, W1a, bb1a, nullptr, nullptr, g1i, be1i, m1i, v1i, g1, be1, m1, v1);

    // ---- readout ----
    graph_mean<<<G, 256, 0, stream>>>(H, gid, N, hg);
    readout_mlp<<<(G + 63) / 64, 256, 0, stream>>>(hg, G, Wr1, br1, Wr2, br2, OUT);
}

// Round 8
// 150.647 us; speedup vs baseline: 9.5897x; 1.1134x over previous
//
#include <hip/hip_runtime.h>

// ---------------------------------------------------------------------------
// GIN forward, bf16 node-feature intermediates (f32 math, f32 outputs).
// d_out layout: [out (G*64) | h (N*64)]
// ws: [xb | Ab | Z0b | Bb (bf16 rows, N*32 uints each) | row_ptr | ebase |
//      cursor | ghist | ebuf(E u32) | hg]
// Bucket = dst >> 7.  Requires N < 65536 (ids pack u16).
// ---------------------------------------------------------------------------

#define EPB 2048
#define MAXB 512

__device__ __forceinline__ unsigned bf16pack(float a, float b) {
    unsigned ua = __float_as_uint(a);
    unsigned ub = __float_as_uint(b);
    ua = (ua + 0x7FFFu + ((ua >> 16) & 1u)) >> 16;
    ub = (ub + 0x7FFFu + ((ub >> 16) & 1u)) & 0xFFFF0000u;
    return ua | ub;
}
__device__ __forceinline__ float bf16lo(unsigned w) { return __uint_as_float(w << 16); }
__device__ __forceinline__ float bf16hi(unsigned w) { return __uint_as_float(w & 0xFFFF0000u); }

// ---- cast x -> bf16 rows, and zero the bucket histogram --------------------
__global__ __launch_bounds__(256) void cast_zero(uint4* __restrict__ xb4,
                                                 const float4* __restrict__ x4,
                                                 int nq, int* __restrict__ gh) {
    if (blockIdx.x == 0) {
        for (int i = threadIdx.x; i < MAXB; i += 256) gh[i] = 0;
    }
    int i = blockIdx.x * 256 + threadIdx.x;
    if (i >= nq) return;
    float4 a = x4[2 * i], b = x4[2 * i + 1];
    uint4 o;
    o.x = bf16pack(a.x, a.y); o.y = bf16pack(a.z, a.w);
    o.z = bf16pack(b.x, b.y); o.w = bf16pack(b.z, b.w);
    xb4[i] = o;
}

// ---- Phase A: global bucket histogram (LDS-aggregated) --------------------
__global__ __launch_bounds__(256) void bucket_hist(int* __restrict__ gh,
                                                   const int* __restrict__ dst,
                                                   int E) {
    __shared__ int h[MAXB];
    const int t = threadIdx.x;
    for (int i = t; i < MAXB; i += 256) h[i] = 0;
    __syncthreads();
    const int base = blockIdx.x * EPB;
#pragma unroll
    for (int i = 0; i < 8; ++i) {
        int e = base + i * 256 + t;
        if (e < E) atomicAdd(&h[dst[e] >> 7], 1);
    }
    __syncthreads();
    for (int i = t; i < MAXB; i += 256) {
        int v = h[i];
        if (v) atomicAdd(&gh[i], v);
    }
}

// ---- Phase B: single-block scan of bucket counts ---------------------------
__global__ __launch_bounds__(1024) void scan_small(const int* __restrict__ in,
                                                   int* __restrict__ ebase,
                                                   int* __restrict__ cursor,
                                                   int n, int total) {
    __shared__ int arr[1024];
    const int t = threadIdx.x;
    int v = (t < n) ? in[t] : 0;
    arr[t] = v;
    __syncthreads();
    for (int s = 1; s < 1024; s <<= 1) {
        int u = (t >= s) ? arr[t - s] : 0;
        __syncthreads();
        arr[t] += u;
        __syncthreads();
    }
    int excl = (t > 0) ? arr[t - 1] : 0;
    if (t < n) {
        ebase[t] = excl;
        cursor[t] = excl;
    }
    if (t == 0) ebase[n] = total;
}

// ---- Phase C: scatter packed (src<<16|dst) into bucket-grouped ebuf -------
__global__ __launch_bounds__(256) void bin_scatter(unsigned* __restrict__ ebuf,
                                                   int* __restrict__ cursor,
                                                   const int* __restrict__ src,
                                                   const int* __restrict__ dst,
                                                   int E) {
    __shared__ int h[MAXB];
    __shared__ int gb[MAXB];
    const int t = threadIdx.x;
    for (int i = t; i < MAXB; i += 256) h[i] = 0;
    __syncthreads();
    const int base = blockIdx.x * EPB;
    int sv[8], dv[8];
#pragma unroll
    for (int i = 0; i < 8; ++i) {
        int e = base + i * 256 + t;
        if (e < E) {
            sv[i] = src[e];
            dv[i] = dst[e];
            atomicAdd(&h[dv[i] >> 7], 1);
        } else {
            dv[i] = -1;
        }
    }
    __syncthreads();
    for (int i = t; i < MAXB; i += 256) {
        int v = h[i];
        gb[i] = v ? atomicAdd(&cursor[i], v) : 0;
        h[i] = 0;
    }
    __syncthreads();
#pragma unroll
    for (int i = 0; i < 8; ++i) {
        if (dv[i] >= 0) {
            int b = dv[i] >> 7;
            int p = atomicAdd(&h[b], 1);
            ebuf[gb[b] + p] = ((unsigned)sv[i] << 16) | (unsigned)dv[i];
        }
    }
}

// ---- Phase D: per-bucket row_ptr + in-place col fill (LDS-staged) ---------
__global__ __launch_bounds__(256) void bucket_fill(unsigned* __restrict__ ebuf,
                                                   const int* __restrict__ ebase,
                                                   int* __restrict__ row_ptr,
                                                   int N, int E) {
    __shared__ unsigned pairLDS[4096];
    __shared__ unsigned colLDS[4096];
    __shared__ int deg[128], off[128], cur[128];
    const int b = blockIdx.x;
    const int t = threadIdx.x;
    const int lo = ebase[b];
    const int hi = ebase[b + 1];
    const int m = hi - lo;
    const int nb0 = b << 7;

    if (t < 128) deg[t] = 0;
    __syncthreads();
    for (int k = t; k < m; k += 256) {
        unsigned v = ebuf[lo + k];
        pairLDS[k] = v;
        atomicAdd(&deg[(int)(v & 0xFFFFu) - nb0], 1);
    }
    __syncthreads();
    if (t < 128) off[t] = deg[t];
    __syncthreads();
    for (int s = 1; s < 128; s <<= 1) {
        int u = 0;
        if (t < 128 && t >= s) u = off[t - s];
        __syncthreads();
        if (t < 128) off[t] += u;
        __syncthreads();
    }
    if (t < 128) {
        int excl = off[t] - deg[t];
        cur[t] = excl;
        int node = nb0 + t;
        if (node <= N) row_ptr[node] = lo + excl;
    }
    __syncthreads();
    for (int k = t; k < m; k += 256) {
        unsigned v = pairLDS[k];
        int dl = (int)(v & 0xFFFFu) - nb0;
        int p = atomicAdd(&cur[dl], 1);
        colLDS[p] = v >> 16;
    }
    __syncthreads();
    for (int k = t; k < m; k += 256) ebuf[lo + k] = colLDS[k];
}

// ---- gather aggregation on bf16 rows: out = (1+eps)*in[n] + sum in[nbr] ---
// One wave per node. lane = (jj = neighbor slot 0..7, q = 16B slot 0..7):
// 8 neighbors in flight, 16B/lane, f32 accumulate, shfl-reduce, bf16 store.
__global__ __launch_bounds__(256) void aggregate_bf16(
    unsigned* __restrict__ outb, const unsigned* __restrict__ inb,
    const int* __restrict__ row_ptr, const unsigned* __restrict__ col,
    const float* __restrict__ eps, int N) {
    const int n = blockIdx.x * 4 + (threadIdx.x >> 6);
    if (n >= N) return;
    const int lane = threadIdx.x & 63;
    const int q = lane & 7;
    const int jj = lane >> 3;
    const int lo = row_ptr[n];
    const int hi = row_ptr[n + 1];
    const uint4* in4 = reinterpret_cast<const uint4*>(inb);

    float a[8];
#pragma unroll
    for (int k = 0; k < 8; ++k) a[k] = 0.f;

    int j = lo;
#pragma unroll 2
    for (; j + 8 <= hi; j += 8) {
        unsigned c = col[j + jj];
        uint4 v = in4[(size_t)c * 8 + q];
        a[0] += bf16lo(v.x); a[1] += bf16hi(v.x);
        a[2] += bf16lo(v.y); a[3] += bf16hi(v.y);
        a[4] += bf16lo(v.z); a[5] += bf16hi(v.z);
        a[6] += bf16lo(v.w); a[7] += bf16hi(v.w);
    }
    if (j + jj < hi) {
        unsigned c = col[j + jj];
        uint4 v = in4[(size_t)c * 8 + q];
        a[0] += bf16lo(v.x); a[1] += bf16hi(v.x);
        a[2] += bf16lo(v.y); a[3] += bf16hi(v.y);
        a[4] += bf16lo(v.z); a[5] += bf16hi(v.z);
        a[6] += bf16lo(v.w); a[7] += bf16hi(v.w);
    }

#pragma unroll
    for (int k = 0; k < 8; ++k) {
        a[k] += __shfl_xor(a[k], 8);
        a[k] += __shfl_xor(a[k], 16);
        a[k] += __shfl_xor(a[k], 32);
    }

    if (jj == 0) {
        float s = 1.0f + eps[0];
        uint4 o = in4[(size_t)n * 8 + q];
        a[0] = fmaf(s, bf16lo(o.x), a[0]); a[1] = fmaf(s, bf16hi(o.x), a[1]);
        a[2] = fmaf(s, bf16lo(o.y), a[2]); a[3] = fmaf(s, bf16hi(o.y), a[3]);
        a[4] = fmaf(s, bf16lo(o.z), a[4]); a[5] = fmaf(s, bf16hi(o.z), a[5]);
        a[6] = fmaf(s, bf16lo(o.w), a[6]); a[7] = fmaf(s, bf16hi(o.w), a[7]);
        uint4 w;
        w.x = bf16pack(a[0], a[1]); w.y = bf16pack(a[2], a[3]);
        w.z = bf16pack(a[4], a[5]); w.w = bf16pack(a[6], a[7]);
        reinterpret_cast<uint4*>(outb)[(size_t)n * 8 + q] = w;
    }
}

// ---- fused GIN MLP: bf16 in, f32 math, bf16 or f32 out ---------------------
template <bool TWO, bool OUTB>
__global__ __launch_bounds__(256) void mlp_fused(
    const unsigned* __restrict__ inb, unsigned* __restrict__ outb,
    float* __restrict__ outf, int N,
    const float* __restrict__ Wa, const float* __restrict__ ba,
    const float* __restrict__ Wb, const float* __restrict__ bb,
    const float* __restrict__ gi, const float* __restrict__ bei,
    const float* __restrict__ mi, const float* __restrict__ vi,
    const float* __restrict__ go, const float* __restrict__ beo,
    const float* __restrict__ mo, const float* __restrict__ vo) {
    constexpr int PITCH = 68;
    __shared__ __align__(16) float Ws1[64 * 64];
    __shared__ __align__(16) float Ws2[TWO ? 64 * 64 : 4];
    __shared__ __align__(16) float Xs[64 * PITCH];
    __shared__ __align__(16) float Ys[TWO ? 64 * PITCH : 4];

    const int t = threadIdx.x;
    const int row0 = blockIdx.x * 64;

#pragma unroll
    for (int j = 0; j < 4; ++j) {
        int f4 = t + 256 * j;
        reinterpret_cast<float4*>(Ws1)[f4] = reinterpret_cast<const float4*>(Wa)[f4];
        if (TWO)
            reinterpret_cast<float4*>(Ws2)[f4] = reinterpret_cast<const float4*>(Wb)[f4];
    }
    {
        int rs = t >> 2;
        int kq = t & 3;
        int grow = row0 + rs;
        const uint4* in4 = reinterpret_cast<const uint4*>(inb);
#pragma unroll
        for (int jj = 0; jj < 2; ++jj) {
            int u4 = kq * 2 + jj;
            uint4 v = make_uint4(0u, 0u, 0u, 0u);
            if (grow < N) v = in4[(size_t)grow * 8 + u4];
            int kb = u4 * 8;
            Xs[(kb + 0) * PITCH + rs] = bf16lo(v.x);
            Xs[(kb + 1) * PITCH + rs] = bf16hi(v.x);
            Xs[(kb + 2) * PITCH + rs] = bf16lo(v.y);
            Xs[(kb + 3) * PITCH + rs] = bf16hi(v.y);
            Xs[(kb + 4) * PITCH + rs] = bf16lo(v.z);
            Xs[(kb + 5) * PITCH + rs] = bf16hi(v.z);
            Xs[(kb + 6) * PITCH + rs] = bf16lo(v.w);
            Xs[(kb + 7) * PITCH + rs] = bf16hi(v.w);
        }
    }
    __syncthreads();

    const int tr = t >> 4;
    const int tc = t & 15;

    float acc[4][4];
#pragma unroll
    for (int i = 0; i < 4; ++i)
#pragma unroll
        for (int j = 0; j < 4; ++j) acc[i][j] = 0.f;

#pragma unroll 4
    for (int k = 0; k < 64; ++k) {
        float4 a = *reinterpret_cast<const float4*>(&Xs[k * PITCH + 4 * tr]);
        float4 b = *reinterpret_cast<const float4*>(&Ws1[k * 64 + 4 * tc]);
        float av[4] = {a.x, a.y, a.z, a.w};
        float bv[4] = {b.x, b.y, b.z, b.w};
#pragma unroll
        for (int i = 0; i < 4; ++i)
#pragma unroll
            for (int j = 0; j < 4; ++j) acc[i][j] = fmaf(av[i], bv[j], acc[i][j]);
    }

    float u[4][4];
#pragma unroll
    for (int i = 0; i < 4; ++i)
#pragma unroll
        for (int j = 0; j < 4; ++j)
            u[i][j] = fmaxf(acc[i][j] + ba[4 * tc + j], 0.f);

    if (TWO) {
#pragma unroll
        for (int j = 0; j < 4; ++j) {
            float4 w = make_float4(u[0][j], u[1][j], u[2][j], u[3][j]);
            *reinterpret_cast<float4*>(&Ys[(4 * tc + j) * PITCH + 4 * tr]) = w;
        }
        __syncthreads();
#pragma unroll
        for (int i = 0; i < 4; ++i)
#pragma unroll
            for (int j = 0; j < 4; ++j) acc[i][j] = 0.f;
#pragma unroll 4
        for (int k = 0; k < 64; ++k) {
            float4 a = *reinterpret_cast<const float4*>(&Ys[k * PITCH + 4 * tr]);
            float4 b = *reinterpret_cast<const float4*>(&Ws2[k * 64 + 4 * tc]);
            float av[4] = {a.x, a.y, a.z, a.w};
            float bv[4] = {b.x, b.y, b.z, b.w};
#pragma unroll
            for (int i = 0; i < 4; ++i)
#pragma unroll
                for (int j = 0; j < 4; ++j) acc[i][j] = fmaf(av[i], bv[j], acc[i][j]);
        }
#pragma unroll
        for (int i = 0; i < 4; ++i)
#pragma unroll
            for (int j = 0; j < 4; ++j)
                u[i][j] = fmaxf(acc[i][j] + bb[4 * tc + j], 0.f);
    }

    float sc[4], sh[4];
#pragma unroll
    for (int j = 0; j < 4; ++j) {
        int c = 4 * tc + j;
        float si = gi[c] * rsqrtf(vi[c] + 1e-5f);
        float ti = bei[c] - mi[c] * si;
        float so = go[c] * rsqrtf(vo[c] + 1e-5f);
        float to = beo[c] - mo[c] * so;
        sc[j] = si * so;
        sh[j] = ti * so + to;
    }
#pragma unroll
    for (int i = 0; i < 4; ++i) {
        int grow = row0 + 4 * tr + i;
        if (grow >= N) continue;
        float y0 = fmaxf(u[i][0] * sc[0] + sh[0], 0.f);
        float y1 = fmaxf(u[i][1] * sc[1] + sh[1], 0.f);
        float y2 = fmaxf(u[i][2] * sc[2] + sh[2], 0.f);
        float y3 = fmaxf(u[i][3] * sc[3] + sh[3], 0.f);
        if (OUTB) {
            uint2 w;
            w.x = bf16pack(y0, y1);
            w.y = bf16pack(y2, y3);
            *reinterpret_cast<uint2*>(outb + (size_t)grow * 32 + tc * 2) = w;
        } else {
            float4 w = make_float4(y0, y1, y2, y3);
            *reinterpret_cast<float4*>(outf + (size_t)grow * 64 + 4 * tc) = w;
        }
    }
}

__device__ __forceinline__ int lbound(const int* __restrict__ a, int n, int v) {
    int lo = 0, hi = n;
    while (lo < hi) {
        int mid = (lo + hi) >> 1;
        if (a[mid] < v) lo = mid + 1;
        else hi = mid;
    }
    return lo;
}

// ---- per-graph mean -------------------------------------------------------
__global__ __launch_bounds__(256) void graph_mean(const float* __restrict__ H,
                                                  const int* __restrict__ gid,
                                                  int N,
                                                  float* __restrict__ hg) {
    __shared__ float part[4][64];
    const int g = blockIdx.x;
    const int lane = threadIdx.x & 63;
    const int w = threadIdx.x >> 6;
    const int lo = lbound(gid, N, g);
    const int hi = lbound(gid, N, g + 1);
    float acc = 0.f;
    for (int r = lo + w; r < hi; r += 4) acc += H[(size_t)r * 64 + lane];
    part[w][lane] = acc;
    __syncthreads();
    if (w == 0) {
        float s = part[0][lane] + part[1][lane] + part[2][lane] + part[3][lane];
        float cnt = fmaxf((float)(hi - lo), 1.0f);
        hg[(size_t)g * 64 + lane] = s / cnt;
    }
}

// ---- readout MLP ------------------------------------------------------------
__global__ __launch_bounds__(256) void readout_mlp(
    const float* __restrict__ hg, int G,
    const float* __restrict__ W1, const float* __restrict__ b1,
    const float* __restrict__ W2, const float* __restrict__ b2,
    float* __restrict__ out) {
    constexpr int PITCH = 68;
    __shared__ __align__(16) float Ws1[64 * 64];
    __shared__ __align__(16) float Ws2[64 * 64];
    __shared__ __align__(16) float Xs[64 * PITCH];
    __shared__ __align__(16) float Ys[64 * PITCH];

    const int t = threadIdx.x;
    const int row0 = blockIdx.x * 64;

#pragma unroll
    for (int j = 0; j < 4; ++j) {
        int f4 = t + 256 * j;
        reinterpret_cast<float4*>(Ws1)[f4] = reinterpret_cast<const float4*>(W1)[f4];
        reinterpret_cast<float4*>(Ws2)[f4] = reinterpret_cast<const float4*>(W2)[f4];
    }
    {
        int rs = t >> 2;
        int kq = t & 3;
        int grow = row0 + rs;
#pragma unroll
        for (int j = 0; j < 4; ++j) {
            int cf4 = kq + 4 * j;
            float4 v = make_float4(0.f, 0.f, 0.f, 0.f);
            if (grow < G)
                v = *reinterpret_cast<const float4*>(hg + (size_t)grow * 64 + cf4 * 4);
            int kb = cf4 * 4;
            Xs[(kb + 0) * PITCH + rs] = v.x;
            Xs[(kb + 1) * PITCH + rs] = v.y;
            Xs[(kb + 2) * PITCH + rs] = v.z;
            Xs[(kb + 3) * PITCH + rs] = v.w;
        }
    }
    __syncthreads();

    const int tr = t >> 4;
    const int tc = t & 15;

    float acc[4][4];
#pragma unroll
    for (int i = 0; i < 4; ++i)
#pragma unroll
        for (int j = 0; j < 4; ++j) acc[i][j] = 0.f;
#pragma unroll 4
    for (int k = 0; k < 64; ++k) {
        float4 a = *reinterpret_cast<const float4*>(&Xs[k * PITCH + 4 * tr]);
        float4 b = *reinterpret_cast<const float4*>(&Ws1[k * 64 + 4 * tc]);
        float av[4] = {a.x, a.y, a.z, a.w};
        float bv[4] = {b.x, b.y, b.z, b.w};
#pragma unroll
        for (int i = 0; i < 4; ++i)
#pragma unroll
            for (int j = 0; j < 4; ++j) acc[i][j] = fmaf(av[i], bv[j], acc[i][j]);
    }
    float u[4][4];
#pragma unroll
    for (int i = 0; i < 4; ++i)
#pragma unroll
        for (int j = 0; j < 4; ++j)
            u[i][j] = fmaxf(acc[i][j] + b1[4 * tc + j], 0.f);

#pragma unroll
    for (int j = 0; j < 4; ++j) {
        float4 w = make_float4(u[0][j], u[1][j], u[2][j], u[3][j]);
        *reinterpret_cast<float4*>(&Ys[(4 * tc + j) * PITCH + 4 * tr]) = w;
    }
    __syncthreads();
#pragma unroll
    for (int i = 0; i < 4; ++i)
#pragma unroll
        for (int j = 0; j < 4; ++j) acc[i][j] = 0.f;
#pragma unroll 4
    for (int k = 0; k < 64; ++k) {
        float4 a = *reinterpret_cast<const float4*>(&Ys[k * PITCH + 4 * tr]);
        float4 b = *reinterpret_cast<const float4*>(&Ws2[k * 64 + 4 * tc]);
        float av[4] = {a.x, a.y, a.z, a.w};
        float bv[4] = {b.x, b.y, b.z, b.w};
#pragma unroll
        for (int i = 0; i < 4; ++i)
#pragma unroll
            for (int j = 0; j < 4; ++j) acc[i][j] = fmaf(av[i], bv[j], acc[i][j]);
    }
#pragma unroll
    for (int i = 0; i < 4; ++i) {
        int grow = row0 + 4 * tr + i;
        if (grow >= G) continue;
        float4 w;
        w.x = acc[i][0] + b2[4 * tc + 0];
        w.y = acc[i][1] + b2[4 * tc + 1];
        w.z = acc[i][2] + b2[4 * tc + 2];
        w.w = acc[i][3] + b2[4 * tc + 3];
        *reinterpret_cast<float4*>(out + (size_t)grow * 64 + 4 * tc) = w;
    }
}

extern "C" void kernel_launch(void* const* d_in, const int* in_sizes, int n_in,
                              void* d_out, int out_size, void* d_ws, size_t ws_size,
                              hipStream_t stream) {
    const float* x    = (const float*)d_in[0];
    const int*   src  = (const int*)d_in[1];
    const int*   dst  = (const int*)d_in[2];
    const int*   gid  = (const int*)d_in[3];
    const float* eps0 = (const float*)d_in[4];
    const float* W0a  = (const float*)d_in[5];
    const float* bb0a = (const float*)d_in[6];
    const float* W0b  = (const float*)d_in[7];
    const float* bb0b = (const float*)d_in[8];
    const float* g0i  = (const float*)d_in[9];
    const float* be0i = (const float*)d_in[10];
    const float* m0i  = (const float*)d_in[11];
    const float* v0i  = (const float*)d_in[12];
    const float* g0   = (const float*)d_in[13];
    const float* be0  = (const float*)d_in[14];
    const float* m0   = (const float*)d_in[15];
    const float* v0   = (const float*)d_in[16];
    const float* eps1 = (const float*)d_in[17];
    const float* W1a  = (const float*)d_in[18];
    const float* bb1a = (const float*)d_in[19];
    const float* g1i  = (const float*)d_in[20];
    const float* be1i = (const float*)d_in[21];
    const float* m1i  = (const float*)d_in[22];
    const float* v1i  = (const float*)d_in[23];
    const float* g1   = (const float*)d_in[24];
    const float* be1  = (const float*)d_in[25];
    const float* m1   = (const float*)d_in[26];
    const float* v1   = (const float*)d_in[27];
    const float* Wr1  = (const float*)d_in[28];
    const float* br1  = (const float*)d_in[29];
    const float* Wr2  = (const float*)d_in[30];
    const float* br2  = (const float*)d_in[31];

    const int N = in_sizes[0] / 64;       // 50000
    const int E = in_sizes[1];            // 800000
    const int G = out_size / 64 - N;      // 500
    const int NB = (N + 127) >> 7;

    // ws layout
    char* ws = (char*)d_ws;
    unsigned* xb      = (unsigned*)ws;     ws += (size_t)N * 32 * 4;
    unsigned* Ab      = (unsigned*)ws;     ws += (size_t)N * 32 * 4;
    unsigned* Z0b     = (unsigned*)ws;     ws += (size_t)N * 32 * 4;
    unsigned* Bb      = (unsigned*)ws;     ws += (size_t)N * 32 * 4;
    int*      row_ptr = (int*)ws;          ws += ((size_t)N + 8) * 4;
    int*      ebase   = (int*)ws;          ws += (MAXB + 4) * 4;
    int*      cursor  = (int*)ws;          ws += (MAXB + 4) * 4;
    int*      ghist   = (int*)ws;          ws += (MAXB + 4) * 4;
    unsigned* ebuf    = (unsigned*)ws;     ws += (size_t)E * 4;
    float*    hg      = (float*)ws;        // G*64

    float* OUT = (float*)d_out;
    float* H   = OUT + (size_t)G * 64;

    const int EB = (E + EPB - 1) / EPB;
    const int NQ = N * 8;  // uint4 outputs in cast

    // ---- cast x->bf16 + zero hist ----
    cast_zero<<<(NQ + 255) / 256, 256, 0, stream>>>(
        (uint4*)xb, (const float4*)x, NQ, ghist);

    // ---- build CSR (bucketed; shared by both layers) ----
    bucket_hist<<<EB, 256, 0, stream>>>(ghist, dst, E);
    scan_small<<<1, 1024, 0, stream>>>(ghist, ebase, cursor, NB, E);
    bin_scatter<<<EB, 256, 0, stream>>>(ebuf, cursor, src, dst, E);
    bucket_fill<<<NB, 256, 0, stream>>>(ebuf, ebase, row_ptr, N, E);

    // ---- GIN layer 0 ----
    aggregate_bf16<<<(N + 3) / 4, 256, 0, stream>>>(Ab, xb, row_ptr, ebuf, eps0, N);
    mlp_fused<true, true><<<(N + 63) / 64, 256, 0, stream>>>(
        Ab, Z0b, nullptr, N, W0a, bb0a, W0b, bb0b,
        g0i, be0i, m0i, v0i, g0, be0, m0, v0);

    // ---- GIN layer 1 ----
    aggregate_bf16<<<(N + 3) / 4, 256, 0, stream>>>(Bb, Z0b, row_ptr, ebuf, eps1, N);
    mlp_fused<false, false><<<(N + 63) / 64, 256, 0, stream>>>(
        Bb, nullptr, H, N, W1a, bb1a, nullptr, nullptr,
        g1i, be1i, m1i, v1i, g1, be1, m1, v1);

    // ---- readout ----
    graph_mean<<<G, 256, 0, stream>>>(H, gid, N, hg);
    readout_mlp<<<(G + 63) / 64, 256, 0, stream>>>(hg, G, Wr1, br1, Wr2, br2, OUT);
}